// Round 7
// baseline (411.583 us; speedup 1.0000x reference)
//
#include <hip/hip_runtime.h>
#include <stdint.h>

#define LN_EPS 1e-5f

// ---------- bf16 helpers (RNE, bit-level) ----------
static __device__ __forceinline__ unsigned short f2bf_bits(float f) {
  union { float f; unsigned u; } v; v.f = f;
  unsigned r = v.u + 0x7FFFu + ((v.u >> 16) & 1u);
  return (unsigned short)(r >> 16);
}
static __device__ __forceinline__ float bf2f(unsigned short h) {
  union { unsigned u; float f; } v; v.u = ((unsigned)h) << 16;
  return v.f;
}

typedef __bf16 bf16x8 __attribute__((ext_vector_type(8)));
typedef float floatx4 __attribute__((ext_vector_type(4)));

// ---------- async global->LDS, 16B per lane ----------
typedef __attribute__((address_space(1))) unsigned int* gas_ptr;
typedef __attribute__((address_space(3))) unsigned int* las_ptr;
static __device__ __forceinline__ void async_cp16(const void* g, void* l) {
  __builtin_amdgcn_global_load_lds((gas_ptr)g, (las_ptr)l, 16, 0, 0);
}

// =====================================================================================
// perm: per batch, stable partition visible-first. newrow[b*4096+n] = within-batch
// destination row; cnt[b] = #visible. Also zeroes bcnt[b] (gemm4's last-block counter)
// each replay.
// =====================================================================================
__global__ __launch_bounds__(256) void perm_kernel(
    const int* __restrict__ mask, int* __restrict__ newrow, int* __restrict__ cnt,
    int* __restrict__ bcnt) {
  const int b = blockIdx.x, t = threadIdx.x;
  const int base = b * 4096 + t * 16;
  int v[16]; int s = 0;
#pragma unroll
  for (int i = 0; i < 16; ++i) { v[i] = (mask[base + i] != 0); s += v[i]; }
  const int lane = t & 63, wv = t >> 6;
  int scan = s;
  for (int o = 1; o < 64; o <<= 1) { int x = __shfl_up(scan, o); if (lane >= o) scan += x; }
  __shared__ int wsum[4], woff[4], stotal;
  if (lane == 63) wsum[wv] = scan;
  __syncthreads();
  if (t == 0) {
    int a = 0; for (int k = 0; k < 4; ++k) { woff[k] = a; a += wsum[k]; }
    stotal = a; cnt[b] = a; bcnt[b] = 0;
  }
  __syncthreads();
  const int excl = scan - s + woff[wv];
  const int total = stotal;
  int run = 0;
#pragma unroll
  for (int i = 0; i < 16; ++i) {
    const int pos = t * 16 + i;
    const int visBefore = excl + run;
    newrow[b * 4096 + pos] = v[i] ? visBefore : total + (pos - visBefore);
    run += v[i];
  }
}

// =====================================================================================
// K_b: conv1 (K=3, fp32 exact) + LayerNorm(128) + mask + relu -> h2 bf16, compacted
// scatter via newrow; visibility == (dest < cnt[b]).  R1-proven 64-lane version.
// Block tail 1 [32768, 32768+2176): fp32->bf16 for w2, w4.
// Block tail 2 [34944, 34944+256): W23 = w3R@w2 (fp32, ->bf16) and vecb = w3R@b2.
// Block tail 3 [35200]: tile lists tl128/tl256 + hdr = {nT128, nT256}.
// =====================================================================================
__global__ __launch_bounds__(256) void conv1_ln_kernel(
    const float* __restrict__ points,
    const float* __restrict__ w1, const float* __restrict__ g1,
    const float* __restrict__ be1, unsigned short* __restrict__ h2,
    const int* __restrict__ newrow, const int* __restrict__ cnt,
    const float* __restrict__ w2, const float* __restrict__ b2,
    const float* __restrict__ w3, const float* __restrict__ w4,
    unsigned short* __restrict__ w2b, unsigned short* __restrict__ w4b,
    unsigned short* __restrict__ w23b, float* __restrict__ vecb,
    int* __restrict__ hdr, unsigned short* __restrict__ tl128,
    unsigned short* __restrict__ tl256) {
  if (blockIdx.x >= 32768) {
    const int bb = blockIdx.x - 32768;
    if (bb < 2176) {              // wconv: w2 (32768) + w4 (524288)
      int idx = bb * 256 + threadIdx.x;
      if (idx < 32768) w2b[idx] = f2bf_bits(w2[idx]);
      else w4b[idx - 32768] = f2bf_bits(w4[idx - 32768]);
    } else if (bb < 2176 + 256) { // W23 = w3[:,256:] @ w2  [512x128], 2 rows per block
      const int tid = threadIdx.x;
      const int p = (bb - 2176) * 2 + (tid >> 7);
      const int c = tid & 127;
      const float* w3r = w3 + (size_t)p * 512 + 256;
      float s = 0.f;
      for (int k = 0; k < 256; ++k) s += w3r[k] * w2[k * 128 + c];
      w23b[p * 128 + c] = f2bf_bits(s);
      if (c == 0) {
        float vb = 0.f;
        for (int k = 0; k < 256; ++k) vb += w3r[k] * b2[k];
        vecb[p] = vb;
      }
    } else {                      // tile lists (wave 0 only)
      const int lane = threadIdx.x;
      if (lane < 64) {
        const int c = (lane < 32) ? cnt[lane] : 0;
        const int n128 = (c + 127) >> 7;
        const int n256 = (c + 255) >> 8;
        int s128 = n128, s256 = n256;
        for (int o = 1; o < 64; o <<= 1) {
          int x = __shfl_up(s128, o); if (lane >= o) s128 += x;
          int y = __shfl_up(s256, o); if (lane >= o) s256 += y;
        }
        if (lane == 31) { hdr[0] = s128; hdr[1] = s256; }
        if (lane < 32) {
          const int e128 = s128 - n128, e256 = s256 - n256;
          for (int j = 0; j < n128; ++j) tl128[e128 + j] = (unsigned short)(lane * 32 + j);
          for (int j = 0; j < n256; ++j) tl256[e256 + j] = (unsigned short)(lane * 16 + j);
        }
      }
    }
    return;
  }
  const int lane = threadIdx.x & 63;
  const int wv = threadIdx.x >> 6;
  const size_t p = (size_t)blockIdx.x * 4 + wv;
  const int dest = newrow[p];
  const int cntb = cnt[p >> 12];
  const int ceilv = (cntb + 127) & ~127;
  if (dest >= ceilv) return;                 // row never read downstream
  const bool vis = (dest < cntb);
  const float x0 = points[p * 3 + 0];
  const float x1 = points[p * 3 + 1];
  const float x2 = points[p * 3 + 2];
  const int c0 = lane * 2, c1 = c0 + 1;
  float h00 = w1[c0 * 3] * x0 + w1[c0 * 3 + 1] * x1 + w1[c0 * 3 + 2] * x2;
  float h01 = w1[c1 * 3] * x0 + w1[c1 * 3 + 1] * x1 + w1[c1 * 3 + 2] * x2;
  float s = h00 + h01;
  for (int o = 32; o; o >>= 1) s += __shfl_xor(s, o);
  const float mu = s * (1.f / 128.f);
  const float d0 = h00 - mu, d1 = h01 - mu;
  float q = d0 * d0 + d1 * d1;
  for (int o = 32; o; o >>= 1) q += __shfl_xor(q, o);
  const float rs = rsqrtf(q * (1.f / 128.f) + LN_EPS);
  const float y0 = vis ? fmaxf(d0 * rs * g1[c0] + be1[c0], 0.f) : 0.f;
  const float y1 = vis ? fmaxf(d1 * rs * g1[c1] + be1[c1], 0.f) : 0.f;
  union { unsigned u; unsigned short s2[2]; } pk;
  pk.s2[0] = f2bf_bits(y0);
  pk.s2[1] = f2bf_bits(y1);
  const size_t prow = (p & ~(size_t)4095) + (size_t)dest;
  ((unsigned*)h2)[prow * 64 + lane] = pk.u;
}

// =====================================================================================
// gemm23_fused: ONE launch over combined 768-col space, A = h2 [M x 128], BK=64 twin
// panels, 128x128 tiles. COMPACT + XCD-BANDED (wI = (gid&7)*cw + gid>>3); direct
// scalar stores for OUT. colTile 0-1 (PG): colmax(h2@w2^T + b2) -> pg. colTile 2-5
// (OUT): h46 = h2@W23^T + vecb.
// =====================================================================================
__global__ __launch_bounds__(256) void gemm23_fused(
    const unsigned short* __restrict__ A,
    const unsigned short* __restrict__ w2b, const unsigned short* __restrict__ w23b,
    unsigned short* __restrict__ h46, float* __restrict__ pg,
    const float* __restrict__ b2, const float* __restrict__ vecb,
    const int* __restrict__ hdr, const unsigned short* __restrict__ tl128) {
  __shared__ __align__(16) char smA[2][128 * 64];
  __shared__ __align__(16) char smB[2][128 * 64];
  __shared__ float lmax[2][128];

  const int nW = hdr[0] * 6;
  const int cw = (nW + 7) >> 3;
  const int slot = blockIdx.x >> 3;
  const int wI = (blockIdx.x & 7) * cw + slot;
  if (slot >= cw || wI >= nW) return;
  const int t6 = wI / 6;
  const int colTile = wI - t6 * 6;
  const int rowTile = tl128[t6];

  const int tid = threadIdx.x;
  const int lane = tid & 63;
  const int w = tid >> 6;
  const int wm = w >> 1, wn = w & 1;

  const bool isPG = (colTile < 2);
  const int colBase = isPG ? colTile * 128 : (colTile - 2) * 128;
  const size_t rowBase = (size_t)rowTile * 128;
  const unsigned short* Bw = isPG ? w2b : w23b;

  floatx4 acc[4][4];
  const floatx4 zero = {0.f, 0.f, 0.f, 0.f};
#pragma unroll
  for (int i = 0; i < 4; ++i)
#pragma unroll
    for (int j = 0; j < 4; ++j) acc[i][j] = zero;

  const int rSub = lane >> 2;
  const int cb16 = (lane & 3) * 16;
  const size_t Kb = 256;   // K=128 bf16
  const char* gA = (const char*)A + (rowBase + (size_t)(w * 32 + rSub)) * Kb + cb16;
  const char* gB = (const char*)Bw + ((size_t)colBase + (size_t)(w * 32 + rSub)) * Kb + cb16;
  char* lA0 = smA[0] + w * 2048;
  char* lA1 = smA[1] + w * 2048;
  char* lB0 = smB[0] + w * 2048;
  char* lB1 = smB[1] + w * 2048;
  const size_t skip16 = 16 * Kb;

  const int fm = lane & 15, fq = lane >> 4;
  const int fOff = fm * 64 + fq * 16;
  const char* pa0 = smA[0] + wm * 64 * 64 + fOff;
  const char* pa1 = smA[1] + wm * 64 * 64 + fOff;
  const char* pb0 = smB[0] + wn * 64 * 64 + fOff;
  const char* pb1 = smB[1] + wn * 64 * 64 + fOff;

  for (int k0 = 0; k0 < 128; k0 += 64) {
    async_cp16(gA, lA0);
    async_cp16(gA + skip16, lA0 + 1024);
    async_cp16(gA + 64, lA1);
    async_cp16(gA + 64 + skip16, lA1 + 1024);
    async_cp16(gB, lB0);
    async_cp16(gB + skip16, lB0 + 1024);
    async_cp16(gB + 64, lB1);
    async_cp16(gB + 64 + skip16, lB1 + 1024);
    gA += 128; gB += 128;
    __syncthreads();
    bf16x8 af0[4], bg0[4], af1[4], bg1[4];
#pragma unroll
    for (int i = 0; i < 4; ++i) af0[i] = *(const bf16x8*)(pa0 + i * 16 * 64);
#pragma unroll
    for (int j = 0; j < 4; ++j) bg0[j] = *(const bf16x8*)(pb0 + j * 16 * 64);
#pragma unroll
    for (int i = 0; i < 4; ++i)
#pragma unroll
      for (int j = 0; j < 4; ++j)
        acc[i][j] = __builtin_amdgcn_mfma_f32_16x16x32_bf16(af0[i], bg0[j], acc[i][j], 0, 0, 0);
#pragma unroll
    for (int i = 0; i < 4; ++i) af1[i] = *(const bf16x8*)(pa1 + i * 16 * 64);
#pragma unroll
    for (int j = 0; j < 4; ++j) bg1[j] = *(const bf16x8*)(pb1 + j * 16 * 64);
#pragma unroll
    for (int i = 0; i < 4; ++i)
#pragma unroll
      for (int j = 0; j < 4; ++j)
        acc[i][j] = __builtin_amdgcn_mfma_f32_16x16x32_bf16(af1[i], bg1[j], acc[i][j], 0, 0, 0);
    __syncthreads();
  }

  if (isPG) {       // colmax(acc + b2), no dense store
    float m4[4] = {-1e30f, -1e30f, -1e30f, -1e30f};
#pragma unroll
    for (int j = 0; j < 4; ++j) {
      const float ex = b2[colBase + wn * 64 + j * 16 + fm];
#pragma unroll
      for (int i = 0; i < 4; ++i)
#pragma unroll
        for (int r = 0; r < 4; ++r) m4[j] = fmaxf(m4[j], acc[i][j][r] + ex);
      m4[j] = fmaxf(m4[j], __shfl_xor(m4[j], 16));
      m4[j] = fmaxf(m4[j], __shfl_xor(m4[j], 32));
    }
    const float sel = (fq == 0) ? m4[0] : (fq == 1) ? m4[1] : (fq == 2) ? m4[2] : m4[3];
    lmax[wm][wn * 64 + fq * 16 + fm] = sel;
    __syncthreads();
    if (tid < 128) {
      const float v = fmaxf(lmax[0][tid], lmax[1][tid]);
      pg[(size_t)rowTile * 256 + colBase + tid] = v;
    }
  } else {          // h46 = acc + vecb
#pragma unroll
    for (int j = 0; j < 4; ++j) {
      const int col = colBase + wn * 64 + j * 16 + fm;
      const float ex = vecb[col];
#pragma unroll
      for (int i = 0; i < 4; ++i) {
        const size_t row0 = rowBase + wm * 64 + i * 16 + fq * 4;
#pragma unroll
        for (int r = 0; r < 4; ++r) {
          h46[(row0 + r) * 512 + col] = f2bf_bits(acc[i][j][r] + ex);
        }
      }
    }
  }
}

// =====================================================================================
// GEMM4 (8-phase): colmax(h46 @ w4^T) -> pmax, + FUSED final reduction (last block
// per batch). 256x256 tile, BK=64, 512 thr (8 waves, 2Mx4N), double-buffered 128 KiB
// dynamic LDS, counted vmcnt, st-swizzle, setprio. R1/R5 mapping (banded over all
// 512 rowTiles, inline cnt skip). All blocks of batch b land on one XCD -> pmax is
// L2-resident for the finishing block. Writers threadfence before device-scope
// atomicAdd(bcnt[b]); last block (prev == ntb*4-1) reduces pmax + b4 -> out[b].
// =====================================================================================
#define G4_BAR() __builtin_amdgcn_s_barrier()
#define G4_LGKM0() asm volatile("s_waitcnt lgkmcnt(0)" ::: "memory")
#define G4_LGKM8() asm volatile("s_waitcnt lgkmcnt(8)" ::: "memory")
#define G4_VM2() asm volatile("s_waitcnt vmcnt(2)" ::: "memory")
#define G4_VM0() asm volatile("s_waitcnt vmcnt(0)" ::: "memory")
#define G4_PRIO1() __builtin_amdgcn_s_setprio(1)
#define G4_PRIO0() __builtin_amdgcn_s_setprio(0)

#define G4_STG(bufi, h4, kt) do { \
  const char* _s = (((h4) < 2) ? srcA : srcB) + (size_t)((h4) & 1) * (128 * 1024) + (size_t)(kt) * 128; \
  char* _d = stDst + (bufi) * 65536 + ((h4) >> 1) * 32768 + ((h4) & 1) * 16384; \
  async_cp16(_s, _d); \
  async_cp16(_s + 64 * 1024, _d + 8192); \
} while (0)

#define G4_LDA(bufi, mh) do { \
  const char* _p = rdA + (bufi) * 65536 + (mh) * 8192; \
  af[0][0] = *(const bf16x8*)(_p + c0);        af[0][1] = *(const bf16x8*)(_p + c1); \
  af[1][0] = *(const bf16x8*)(_p + 2048 + c0); af[1][1] = *(const bf16x8*)(_p + 2048 + c1); \
  af[2][0] = *(const bf16x8*)(_p + 4096 + c0); af[2][1] = *(const bf16x8*)(_p + 4096 + c1); \
  af[3][0] = *(const bf16x8*)(_p + 6144 + c0); af[3][1] = *(const bf16x8*)(_p + 6144 + c1); \
} while (0)

#define G4_LDB(bufi, nh, bgx) do { \
  const char* _p = rdB + (bufi) * 65536 + (nh) * 4096; \
  bgx[0][0] = *(const bf16x8*)(_p + c0);        bgx[0][1] = *(const bf16x8*)(_p + c1); \
  bgx[1][0] = *(const bf16x8*)(_p + 2048 + c0); bgx[1][1] = *(const bf16x8*)(_p + 2048 + c1); \
} while (0)

#define G4_QUAD(mh, nh, bgx) do { \
  _Pragma("unroll") \
  for (int _m = 0; _m < 4; ++_m) { \
    _Pragma("unroll") \
    for (int _n = 0; _n < 2; ++_n) { \
      acc[(mh) * 4 + _m][(nh) * 2 + _n] = __builtin_amdgcn_mfma_f32_16x16x32_bf16( \
          af[_m][0], bgx[_n][0], acc[(mh) * 4 + _m][(nh) * 2 + _n], 0, 0, 0); \
      acc[(mh) * 4 + _m][(nh) * 2 + _n] = __builtin_amdgcn_mfma_f32_16x16x32_bf16( \
          af[_m][1], bgx[_n][1], acc[(mh) * 4 + _m][(nh) * 2 + _n], 0, 0, 0); \
    } \
  } \
} while (0)

__global__ __launch_bounds__(512, 2) void gemm4_8ph(
    const unsigned short* __restrict__ A, const unsigned short* __restrict__ Bw,
    float* __restrict__ outp2, const int* __restrict__ cnt,
    int* __restrict__ bcnt, const float* __restrict__ b4,
    float* __restrict__ out) {
  extern __shared__ char sm[];   // 128 KiB: buf{0,1} x (A 32K | B 32K)

  const int gid = blockIdx.x;
  const int xcd = gid & 7;
  const int slot = gid >> 3;
  const int rowTile = xcd * 64 + (slot >> 2);   // 512 rowTiles, banded per XCD
  const int colTile = slot & 3;
  const size_t rowBase = (size_t)rowTile * 256;
  const int colBase = colTile * 256;

  const int cntb = cnt[rowBase >> 12];
  const int rb = (int)(rowBase & 4095);
  if (rb >= cntb) return;                       // fused final is cnt-bounded

  const int tid = threadIdx.x;
  const int lane = tid & 63;
  const int w = tid >> 6;
  const int wm = w >> 2, wn = w & 3;

  // ---- staging addressing: LDS linear dest, global source pre-swizzled ----
  const int rr = tid >> 3;                            // 0..63: row within half (j=0)
  const int csw = ((tid & 7) ^ (rr & 7)) << 4;        // swizzled 16B chunk in 128B row
  const char* srcA = (const char*)A + (rowBase + (size_t)rr) * 1024 + csw;
  const char* srcB = (const char*)Bw + ((size_t)colBase + (size_t)rr) * 1024 + csw;
  char* stDst = sm + w * 1024;                        // wave-uniform; HW adds lane*16

  // ---- read addressing (swizzled ds_read) ----
  const int fr = lane & 15, fq = lane >> 4;
  const int c0 = (fq * 16) ^ ((lane & 7) << 4);
  const int c1 = ((fq * 16) | 64) ^ ((lane & 7) << 4);
  const char* rdA = sm + (wm * 128 + fr) * 128;       // + buf*65536 + mh*8192 + m*2048
  const char* rdB = sm + 32768 + (wn * 64 + fr) * 128;

  floatx4 acc[8][4];
  const floatx4 zero = {0.f, 0.f, 0.f, 0.f};
#pragma unroll
  for (int i = 0; i < 8; ++i)
#pragma unroll
    for (int j = 0; j < 4; ++j) acc[i][j] = zero;

  bf16x8 af[4][2], bg0[2][2], bg1[2][2];

  // prologue: tile0 fully -> buf0; tile1.h0 -> buf1; wait tile0 (leave 2 in flight)
  G4_STG(0, 0, 0); G4_STG(0, 1, 0); G4_STG(0, 2, 0); G4_STG(0, 3, 0);
  G4_STG(1, 0, 1);
  G4_VM2(); G4_BAR();

  for (int it = 0; it < 3; ++it) {
    const int tO = 2 * it + 1, tE2 = 2 * it + 2, tO2 = 2 * it + 3;
    // ph1: E quad(0,0)
    G4_LDA(0, 0); G4_LDB(0, 0, bg0); G4_STG(1, 1, tO); G4_LGKM8(); G4_BAR(); G4_LGKM0();
    G4_PRIO1(); G4_QUAD(0, 0, bg0); G4_PRIO0(); G4_BAR();
    // ph2: E quad(0,1)
    G4_LDB(0, 1, bg1); G4_STG(1, 2, tO); G4_BAR(); G4_LGKM0();
    G4_PRIO1(); G4_QUAD(0, 1, bg1); G4_PRIO0(); G4_BAR();
    // ph3: E quad(1,1)
    G4_LDA(0, 1); G4_STG(1, 3, tO); G4_BAR(); G4_LGKM0();
    G4_PRIO1(); G4_QUAD(1, 1, bg1); G4_PRIO0(); G4_BAR();
    // ph4: E quad(1,0)  [regs only; buf0 free -> start tE2; wait O tile landed]
    G4_STG(0, 0, tE2); G4_VM2(); G4_BAR();
    G4_PRIO1(); G4_QUAD(1, 0, bg0); G4_PRIO0(); G4_BAR();
    // ph5: O quad(0,0)
    G4_LDA(1, 0); G4_LDB(1, 0, bg0); G4_STG(0, 1, tE2); G4_LGKM8(); G4_BAR(); G4_LGKM0();
    G4_PRIO1(); G4_QUAD(0, 0, bg0); G4_PRIO0(); G4_BAR();
    // ph6: O quad(0,1)
    G4_LDB(1, 1, bg1); G4_STG(0, 2, tE2); G4_BAR(); G4_LGKM0();
    G4_PRIO1(); G4_QUAD(0, 1, bg1); G4_PRIO0(); G4_BAR();
    // ph7: O quad(1,1)
    G4_LDA(1, 1); G4_STG(0, 3, tE2); G4_BAR(); G4_LGKM0();
    G4_PRIO1(); G4_QUAD(1, 1, bg1); G4_PRIO0(); G4_BAR();
    // ph8: O quad(1,0)  [buf1 free -> start tO2; wait tE2 landed]
    G4_STG(1, 0, tO2); G4_VM2(); G4_BAR();
    G4_PRIO1(); G4_QUAD(1, 0, bg0); G4_PRIO0(); G4_BAR();
  }

  // drain iteration: tiles 6 (buf0) and 7 (buf1)
  G4_LDA(0, 0); G4_LDB(0, 0, bg0); G4_STG(1, 1, 7); G4_LGKM8(); G4_BAR(); G4_LGKM0();
  G4_PRIO1(); G4_QUAD(0, 0, bg0); G4_PRIO0(); G4_BAR();
  G4_LDB(0, 1, bg1); G4_STG(1, 2, 7); G4_BAR(); G4_LGKM0();
  G4_PRIO1(); G4_QUAD(0, 1, bg1); G4_PRIO0(); G4_BAR();
  G4_LDA(0, 1); G4_STG(1, 3, 7); G4_BAR(); G4_LGKM0();
  G4_PRIO1(); G4_QUAD(1, 1, bg1); G4_PRIO0(); G4_BAR();
  G4_VM0(); G4_BAR();
  G4_PRIO1(); G4_QUAD(1, 0, bg0); G4_PRIO0(); G4_BAR();
  G4_LDA(1, 0); G4_LDB(1, 0, bg0); G4_BAR(); G4_LGKM0();
  G4_PRIO1(); G4_QUAD(0, 0, bg0); G4_PRIO0(); G4_BAR();
  G4_LDB(1, 1, bg1); G4_BAR(); G4_LGKM0();
  G4_PRIO1(); G4_QUAD(0, 1, bg1); G4_PRIO0(); G4_BAR();
  G4_LDA(1, 1); G4_BAR(); G4_LGKM0();
  G4_PRIO1(); G4_QUAD(1, 1, bg1); G4_PRIO0(); G4_BAR();
  G4_PRIO1(); G4_QUAD(1, 0, bg0); G4_PRIO0(); G4_BAR();

  // ---- colmax epilogue (reuse LDS as float scratch; all buffer reads done) ----
  float* smf = (float*)sm;
  float mv[4];
#pragma unroll
  for (int nj = 0; nj < 4; ++nj) {
    float m = -1e30f;
#pragma unroll
    for (int mi = 0; mi < 8; ++mi)
#pragma unroll
      for (int r = 0; r < 4; ++r) m = fmaxf(m, acc[mi][nj][r]);
    m = fmaxf(m, __shfl_xor(m, 16));
    m = fmaxf(m, __shfl_xor(m, 32));
    mv[nj] = m;
  }
  const float sel = (fq == 0) ? mv[0] : (fq == 1) ? mv[1] : (fq == 2) ? mv[2] : mv[3];
  smf[wm * 256 + wn * 64 + fq * 16 + fr] = sel;
  __syncthreads();
  if (tid < 256) {
    outp2[(size_t)rowTile * 1024 + colBase + tid] = fmaxf(smf[tid], smf[256 + tid]);
  }

  // ---- fused final: last block of batch b reduces pmax -> out[b] ----
  __threadfence();                      // make this block's pmax writes visible
  __syncthreads();                      // order tid0's atomic after all fences
  int* flagp = (int*)(sm + 8192);       // free LDS (epilogue used first 2KB)
  const int b = (int)(rowBase >> 12);
  const int ntb = (cntb + 255) >> 8;
  if (tid == 0) {
    const int prev = atomicAdd(&bcnt[b], 1);
    *flagp = (prev == ntb * 4 - 1) ? 1 : 0;
  }
  __syncthreads();
  if (*flagp) {
    __threadfence();                    // acquire: other blocks' pmax now visible
    const float basev = (cntb < 4096) ? 0.f : -1e30f;
    for (int f0 = tid; f0 < 1024; f0 += 512) {
      float m = basev;
      for (int r = 0; r < ntb; ++r)
        m = fmaxf(m, outp2[((size_t)(b * 16 + r)) * 1024 + f0]);
      out[b * 1024 + f0] = m + b4[f0];
    }
  }
}

// =====================================================================================
// Fused gmax reduce + cvec, COALESCED GEMV. 128 blocks (4/batch). Per block:
// gm[t] = max over only the ceil(cnt/128) real pg slots, with b2 baseline (invisible
// rows contribute exactly b2); then wave-per-row dot: lane holds w3[p][lane*4..+4]
// (float4, coalesced) x gm (from LDS), shuffle-reduce over 64.
// =====================================================================================
__global__ __launch_bounds__(256) void gmax_cvec_kernel(
    const float* __restrict__ pg, const float* __restrict__ w3,
    float* __restrict__ cvec, const int* __restrict__ cnt,
    const float* __restrict__ b2) {
  __shared__ float gm[256];
  const int b = blockIdx.x >> 2, quarter = blockIdx.x & 3;
  const int t = threadIdx.x;
  const int c = cnt[b];
  const int nt = (c + 127) >> 7;
  float m = (c < 4096) ? b2[t] : -1e30f;
  for (int s = 0; s < nt; ++s) m = fmaxf(m, pg[((size_t)b * 32 + s) * 256 + t]);
  gm[t] = m;
  __syncthreads();
  const int lane = t & 63, wv = t >> 6;
  const float g0 = gm[lane * 4 + 0];
  const float g1 = gm[lane * 4 + 1];
  const float g2v = gm[lane * 4 + 2];
  const float g3 = gm[lane * 4 + 3];
  for (int pp = 0; pp < 32; ++pp) {
    const int p = quarter * 128 + wv * 32 + pp;
    const float4 wr = *(const float4*)(w3 + (size_t)p * 512 + lane * 4);
    float s = wr.x * g0 + wr.y * g1 + wr.z * g2v + wr.w * g3;
    for (int o = 32; o; o >>= 1) s += __shfl_xor(s, o);
    if (lane == 0) cvec[b * 512 + p] = s;
  }
}

// =====================================================================================
// K_h: (+cvec) + LayerNorm(512) + relu in place on h46 (compacted). COMPACT grid via
// tl256: block i -> tile tl256[i>>6], rows (i&63)*4 + wave. rows < cnt: LN+relu;
// rows [cnt, ceil256): zero (gemm4 reads 256-row tiles).
// =====================================================================================
__global__ __launch_bounds__(256) void ln2_kernel(
    unsigned short* __restrict__ h46, const int* __restrict__ cnt,
    const float* __restrict__ cvec,
    const float* __restrict__ g2, const float* __restrict__ be2,
    const int* __restrict__ hdr, const unsigned short* __restrict__ tl256) {
  const int nW = hdr[1] * 64;
  if (blockIdx.x >= nW) return;
  const int rowTile = tl256[blockIdx.x >> 6];
  const int lane = threadIdx.x & 63;
  const int wv = threadIdx.x >> 6;
  const size_t p = (size_t)rowTile * 256 + ((blockIdx.x & 63) * 4 + wv);
  const int b = rowTile >> 4;
  const int cb = cnt[b];
  const int pin = (int)(p & 4095);
  unsigned short* row = h46 + p * 512;
  const int c0 = lane * 8;
  if (pin >= cb) {                            // straddle zero-fill
    const uint4 z = {0, 0, 0, 0};
    *(uint4*)(row + c0) = z;
    return;
  }
  union { uint4 v; unsigned short s[8]; } in;
  in.v = *(const uint4*)(row + c0);
  float cv[8];
  *(float4*)(cv) = *(const float4*)(cvec + b * 512 + c0);
  *(float4*)(cv + 4) = *(const float4*)(cvec + b * 512 + c0 + 4);
  float f[8];
  float s = 0.f;
#pragma unroll
  for (int k = 0; k < 8; ++k) { f[k] = bf2f(in.s[k]) + cv[k]; s += f[k]; }
  for (int o = 32; o; o >>= 1) s += __shfl_xor(s, o);
  const float mu = s * (1.f / 512.f);
  float q = 0.f;
#pragma unroll
  for (int k = 0; k < 8; ++k) { const float d = f[k] - mu; q += d * d; }
  for (int o = 32; o; o >>= 1) q += __shfl_xor(q, o);
  const float rs = rsqrtf(q * (1.f / 512.f) + LN_EPS);
  union { uint4 v; unsigned short s[8]; } outv;
#pragma unroll
  for (int k = 0; k < 8; ++k) {
    const float y = fmaxf((f[k] - mu) * rs * g2[c0 + k] + be2[c0 + k], 0.f);
    outv.s[k] = f2bf_bits(y);
  }
  *(uint4*)(row + c0) = outv.v;
}

// =====================================================================================
extern "C" void kernel_launch(void* const* d_in, const int* in_sizes, int n_in,
                              void* d_out, int out_size, void* d_ws, size_t ws_size,
                              hipStream_t stream) {
  const float* points = (const float*)d_in[0];
  const int* mask = (const int*)d_in[1];
  const float* w1 = (const float*)d_in[2];
  const float* g1 = (const float*)d_in[3];
  const float* be1 = (const float*)d_in[4];
  const float* w2 = (const float*)d_in[5];
  const float* b2 = (const float*)d_in[6];
  const float* w3 = (const float*)d_in[7];
  const float* g2 = (const float*)d_in[8];
  const float* be2 = (const float*)d_in[9];
  const float* w4 = (const float*)d_in[10];
  const float* b4 = (const float*)d_in[11];
  float* out = (float*)d_out;
  char* ws = (char*)d_ws;

  const size_t OFF_H46 = 0;                          // 134217728 B (bf16 131072x512)
  const size_t OFF_H2 = 134217728;                   //  33554432 B (bf16 131072x128)
  const size_t OFF_W2B = OFF_H2 + 33554432;          //     65536 B
  const size_t OFF_W4B = OFF_W2B + 65536;            //   1048576 B
  const size_t OFF_W23B = OFF_W4B + 1048576;         //    131072 B (bf16 512x128)
  const size_t OFF_VECB = OFF_W23B + 131072;         //      2048 B (f32 512)
  const size_t OFF_PG = OFF_VECB + 2048;             //   1048576 B (f32 1024x256)
  const size_t OFF_CVEC = OFF_PG + 1048576;          //     65536 B
  const size_t OFF_PMAX = OFF_CVEC + 65536;          //   4194304 B (uses 2 MB)
  const size_t OFF_CNT = OFF_PMAX + 4194304;         //      4096 B
  const size_t OFF_NEWROW = OFF_CNT + 4096;          //    524288 B
  const size_t OFF_HDR = OFF_NEWROW + 524288;        //        64 B (nT128, nT256)
  const size_t OFF_TL128 = OFF_HDR + 64;             //      2048 B (u16 x 1024)
  const size_t OFF_TL256 = OFF_TL128 + 2048;         //      1024 B (u16 x 512)
  const size_t OFF_BCNT = OFF_TL256 + 1024;          //       128 B (i32 x 32)

  unsigned short* h2 = (unsigned short*)(ws + OFF_H2);
  unsigned short* h46 = (unsigned short*)(ws + OFF_H46);
  unsigned short* w2b = (unsigned short*)(ws + OFF_W2B);
  unsigned short* w4b = (unsigned short*)(ws + OFF_W4B);
  unsigned short* w23b = (unsigned short*)(ws + OFF_W23B);
  float* vecb = (float*)(ws + OFF_VECB);
  float* pg = (float*)(ws + OFF_PG);
  float* cvecp = (float*)(ws + OFF_CVEC);
  float* pmaxp = (float*)(ws + OFF_PMAX);
  int* cntp = (int*)(ws + OFF_CNT);
  int* newrow = (int*)(ws + OFF_NEWROW);
  int* hdr = (int*)(ws + OFF_HDR);
  unsigned short* tl128 = (unsigned short*)(ws + OFF_TL128);
  unsigned short* tl256 = (unsigned short*)(ws + OFF_TL256);
  int* bcntp = (int*)(ws + OFF_BCNT);

  // one-time: allow 128 KiB dynamic LDS for the 8-phase GEMM (host config, not a
  // stream op -- graph-capture safe)
  static bool s_attr_done = false;
  if (!s_attr_done) {
    hipFuncSetAttribute((const void*)gemm4_8ph,
                        hipFuncAttributeMaxDynamicSharedMemorySize, 131072);
    s_attr_done = true;
  }

  // 0. visible-first compaction map per batch (+ zero gemm4's last-block counters)
  perm_kernel<<<32, 256, 0, stream>>>(mask, newrow, cntp, bcntp);
  // 1. conv1+LN1+relu -> h2 (64-lane, proven); tails: wconv, W23/vecb, tile lists
  conv1_ln_kernel<<<32768 + 2176 + 256 + 1, 256, 0, stream>>>(
      points, w1, g1, be1, h2, newrow, cntp, w2, b2, w3, w4, w2b, w4b, w23b, vecb,
      hdr, tl128, tl256);
  // 2. fused: pg = colmax(h2@w2^T + b2)  AND  h46 = h2@W23^T + vecb  (compact+banded)
  gemm23_fused<<<6144, 256, 0, stream>>>(h2, w2b, w23b, h46, pg, b2, vecb, hdr, tl128);
  // 3. gmax + cvec (coalesced GEMV, 128 blocks, cnt-bounded with b2 baseline)
  gmax_cvec_kernel<<<128, 256, 0, stream>>>(pg, w3, cvecp, cntp, b2);
  // 4. (+cvec) + LN2 + relu in place; zero straddle rows [cnt, ceil256) (compact grid)
  ln2_kernel<<<32768, 256, 0, stream>>>(h46, cntp, cvecp, g2, be2, hdr, tl256);
  // 5. h7 colmax -> pmax + FUSED final reduction (last block per batch -> out)
  gemm4_8ph<<<2048, 512, 131072, stream>>>(h46, w4b, pmaxp, cntp, bcntp, b4, out);
}

// Round 8
// 270.624 us; speedup vs baseline: 1.5209x; 1.5209x over previous
//
#include <hip/hip_runtime.h>
#include <stdint.h>

#define LN_EPS 1e-5f

// ---------- bf16 helpers (RNE, bit-level) ----------
static __device__ __forceinline__ unsigned short f2bf_bits(float f) {
  union { float f; unsigned u; } v; v.f = f;
  unsigned r = v.u + 0x7FFFu + ((v.u >> 16) & 1u);
  return (unsigned short)(r >> 16);
}
static __device__ __forceinline__ float bf2f(unsigned short h) {
  union { unsigned u; float f; } v; v.u = ((unsigned)h) << 16;
  return v.f;
}

typedef __bf16 bf16x8 __attribute__((ext_vector_type(8)));
typedef float floatx4 __attribute__((ext_vector_type(4)));

// ---------- async global->LDS, 16B per lane ----------
typedef __attribute__((address_space(1))) unsigned int* gas_ptr;
typedef __attribute__((address_space(3))) unsigned int* las_ptr;
static __device__ __forceinline__ void async_cp16(const void* g, void* l) {
  __builtin_amdgcn_global_load_lds((gas_ptr)g, (las_ptr)l, 16, 0, 0);
}

// =====================================================================================
// perm: per batch, stable partition visible-first. newrow[b*4096+n] = within-batch
// destination row; cnt[b] = #visible.
// =====================================================================================
__global__ __launch_bounds__(256) void perm_kernel(
    const int* __restrict__ mask, int* __restrict__ newrow, int* __restrict__ cnt) {
  const int b = blockIdx.x, t = threadIdx.x;
  const int base = b * 4096 + t * 16;
  int v[16]; int s = 0;
#pragma unroll
  for (int i = 0; i < 16; ++i) { v[i] = (mask[base + i] != 0); s += v[i]; }
  const int lane = t & 63, wv = t >> 6;
  int scan = s;
  for (int o = 1; o < 64; o <<= 1) { int x = __shfl_up(scan, o); if (lane >= o) scan += x; }
  __shared__ int wsum[4], woff[4], stotal;
  if (lane == 63) wsum[wv] = scan;
  __syncthreads();
  if (t == 0) { int a = 0; for (int k = 0; k < 4; ++k) { woff[k] = a; a += wsum[k]; } stotal = a; cnt[b] = a; }
  __syncthreads();
  const int excl = scan - s + woff[wv];
  const int total = stotal;
  int run = 0;
#pragma unroll
  for (int i = 0; i < 16; ++i) {
    const int pos = t * 16 + i;
    const int visBefore = excl + run;
    newrow[b * 4096 + pos] = v[i] ? visBefore : total + (pos - visBefore);
    run += v[i];
  }
}

// =====================================================================================
// K_b: conv1 (K=3, fp32 exact) + LayerNorm(128) + mask + relu -> h2 bf16, compacted
// scatter via newrow; visibility == (dest < cnt[b]).  R1-proven 64-lane version.
// Block tail 1 [32768, 32768+2176): fp32->bf16 for w2, w4.
// Block tail 2 [34944, 34944+256): W23 = w3R@w2 (fp32, ->bf16) and vecb = w3R@b2.
// =====================================================================================
__global__ __launch_bounds__(256) void conv1_ln_kernel(
    const float* __restrict__ points,
    const float* __restrict__ w1, const float* __restrict__ g1,
    const float* __restrict__ be1, unsigned short* __restrict__ h2,
    const int* __restrict__ newrow, const int* __restrict__ cnt,
    const float* __restrict__ w2, const float* __restrict__ b2,
    const float* __restrict__ w3, const float* __restrict__ w4,
    unsigned short* __restrict__ w2b, unsigned short* __restrict__ w4b,
    unsigned short* __restrict__ w23b, float* __restrict__ vecb) {
  if (blockIdx.x >= 32768) {
    const int bb = blockIdx.x - 32768;
    if (bb < 2176) {              // wconv: w2 (32768) + w4 (524288)
      int idx = bb * 256 + threadIdx.x;
      if (idx < 32768) w2b[idx] = f2bf_bits(w2[idx]);
      else w4b[idx - 32768] = f2bf_bits(w4[idx - 32768]);
    } else {                      // W23 = w3[:,256:] @ w2  [512x128], 2 rows per block
      const int tid = threadIdx.x;
      const int p = (bb - 2176) * 2 + (tid >> 7);
      const int c = tid & 127;
      const float* w3r = w3 + (size_t)p * 512 + 256;
      float s = 0.f;
      for (int k = 0; k < 256; ++k) s += w3r[k] * w2[k * 128 + c];
      w23b[p * 128 + c] = f2bf_bits(s);
      if (c == 0) {
        float vb = 0.f;
        for (int k = 0; k < 256; ++k) vb += w3r[k] * b2[k];
        vecb[p] = vb;
      }
    }
    return;
  }
  const int lane = threadIdx.x & 63;
  const int wv = threadIdx.x >> 6;
  const size_t p = (size_t)blockIdx.x * 4 + wv;
  const int dest = newrow[p];
  const int cntb = cnt[p >> 12];
  const int ceilv = (cntb + 127) & ~127;
  if (dest >= ceilv) return;                 // row never read downstream
  const bool vis = (dest < cntb);
  const float x0 = points[p * 3 + 0];
  const float x1 = points[p * 3 + 1];
  const float x2 = points[p * 3 + 2];
  const int c0 = lane * 2, c1 = c0 + 1;
  float h00 = w1[c0 * 3] * x0 + w1[c0 * 3 + 1] * x1 + w1[c0 * 3 + 2] * x2;
  float h01 = w1[c1 * 3] * x0 + w1[c1 * 3 + 1] * x1 + w1[c1 * 3 + 2] * x2;
  float s = h00 + h01;
  for (int o = 32; o; o >>= 1) s += __shfl_xor(s, o);
  const float mu = s * (1.f / 128.f);
  const float d0 = h00 - mu, d1 = h01 - mu;
  float q = d0 * d0 + d1 * d1;
  for (int o = 32; o; o >>= 1) q += __shfl_xor(q, o);
  const float rs = rsqrtf(q * (1.f / 128.f) + LN_EPS);
  const float y0 = vis ? fmaxf(d0 * rs * g1[c0] + be1[c0], 0.f) : 0.f;
  const float y1 = vis ? fmaxf(d1 * rs * g1[c1] + be1[c1], 0.f) : 0.f;
  union { unsigned u; unsigned short s2[2]; } pk;
  pk.s2[0] = f2bf_bits(y0);
  pk.s2[1] = f2bf_bits(y1);
  const size_t prow = (p & ~(size_t)4095) + (size_t)dest;
  ((unsigned*)h2)[prow * 64 + lane] = pk.u;
}

// =====================================================================================
// gemm23_fused (A-RESIDENT PAIRED): A = h2 [M x 128] staged ONCE per block into a
// resident 32KB 4-panel LDS region; each block processes ONE rowTile x ONE colTile
// PAIR: pair0 = PG cols {0,128} (Bw=w2b, colmax(+b2) -> pg), pair1 = OUT cols {0,128},
// pair2 = OUT cols {256,384} (Bw=w23b, h46 = h2@W23^T + vecb). Grid 3072, XCD-banded
// (xcd = gid&7, rowTile = xcd*128 + slot/3, pair = slot%3). Inner loop per phase is
// byte-identical MFMA order to the proven R1 kernel (numerics unchanged). Skip tiles
// (rb >= cnt) exit without writes (gmax/final are cnt-bounded).
// LDS: 32KB A + 16KB B + 1KB lmax = 49KB -> 3 blocks/CU (12 waves).
// =====================================================================================
__global__ __launch_bounds__(256) void gemm23_fused(
    const unsigned short* __restrict__ A,
    const unsigned short* __restrict__ w2b, const unsigned short* __restrict__ w23b,
    unsigned short* __restrict__ h46, float* __restrict__ pg,
    const float* __restrict__ b2, const float* __restrict__ vecb,
    const int* __restrict__ cnt) {
  __shared__ __align__(16) char smA[4][128 * 64];   // resident A, K quarters (8KB ea)
  __shared__ __align__(16) char smB[2][128 * 64];   // B twin panels per k-step
  __shared__ float lmax[2][128];

  const int gid = blockIdx.x;
  const int xcd = gid & 7;
  const int slot = gid >> 3;                  // 0..383
  const int rowTile = xcd * 128 + slot / 3;   // 1024 rowTiles, banded per XCD
  const int pair = slot - (slot / 3) * 3;     // 0=PG{0,128}, 1=OUT{0,128}, 2=OUT{256,384}
  const size_t rowBase = (size_t)rowTile * 128;

  const int cntb = cnt[rowBase >> 12];
  const int rb = (int)(rowBase & 4095);
  if (rb >= cntb) return;                     // downstream readers are cnt-bounded

  const int tid = threadIdx.x;
  const int lane = tid & 63;
  const int w = tid >> 6;
  const int wm = w >> 1, wn = w & 1;

  const bool isPG = (pair == 0);
  const unsigned short* Bw = isPG ? w2b : w23b;

  const int rSub = lane >> 2;
  const int cb16 = (lane & 3) * 16;
  const size_t skip16 = 16 * 256;             // 16 rows x 256 B/row

  // ---- prologue: stage full-K A panel (8 x cp16/thread), resident for both phases --
  const char* gA = (const char*)A + (rowBase + (size_t)(w * 32 + rSub)) * 256 + cb16;
#pragma unroll
  for (int q = 0; q < 4; ++q) {
    async_cp16(gA + q * 64, smA[q] + w * 2048);
    async_cp16(gA + q * 64 + skip16, smA[q] + w * 2048 + 1024);
  }

  char* lB0 = smB[0] + w * 2048;
  char* lB1 = smB[1] + w * 2048;

  const int fm = lane & 15, fq = lane >> 4;
  const int fOff = fm * 64 + fq * 16;
  const char* pb0 = smB[0] + wn * 64 * 64 + fOff;
  const char* pb1 = smB[1] + wn * 64 * 64 + fOff;

  const floatx4 zero = {0.f, 0.f, 0.f, 0.f};

  for (int ph = 0; ph < 2; ++ph) {
    const int bRow = isPG ? ph * 128 : ((pair - 1) * 256 + ph * 128);
    floatx4 acc[4][4];
#pragma unroll
    for (int i = 0; i < 4; ++i)
#pragma unroll
      for (int j = 0; j < 4; ++j) acc[i][j] = zero;

    const char* gB = (const char*)Bw + ((size_t)(bRow + w * 32 + rSub)) * 256 + cb16;

    for (int k0i = 0; k0i < 2; ++k0i) {
      async_cp16(gB, lB0);
      async_cp16(gB + skip16, lB0 + 1024);
      async_cp16(gB + 64, lB1);
      async_cp16(gB + 64 + skip16, lB1 + 1024);
      gB += 128;
      __syncthreads();          // compiler drains vmcnt before barrier: A+B staged
      const char* pa0 = smA[2 * k0i] + wm * 64 * 64 + fOff;
      const char* pa1 = smA[2 * k0i + 1] + wm * 64 * 64 + fOff;
      bf16x8 af0[4], bg0[4], af1[4], bg1[4];
#pragma unroll
      for (int i = 0; i < 4; ++i) af0[i] = *(const bf16x8*)(pa0 + i * 16 * 64);
#pragma unroll
      for (int j = 0; j < 4; ++j) bg0[j] = *(const bf16x8*)(pb0 + j * 16 * 64);
#pragma unroll
      for (int i = 0; i < 4; ++i)
#pragma unroll
        for (int j = 0; j < 4; ++j)
          acc[i][j] = __builtin_amdgcn_mfma_f32_16x16x32_bf16(af0[i], bg0[j], acc[i][j], 0, 0, 0);
#pragma unroll
      for (int i = 0; i < 4; ++i) af1[i] = *(const bf16x8*)(pa1 + i * 16 * 64);
#pragma unroll
      for (int j = 0; j < 4; ++j) bg1[j] = *(const bf16x8*)(pb1 + j * 16 * 64);
#pragma unroll
      for (int i = 0; i < 4; ++i)
#pragma unroll
        for (int j = 0; j < 4; ++j)
          acc[i][j] = __builtin_amdgcn_mfma_f32_16x16x32_bf16(af1[i], bg1[j], acc[i][j], 0, 0, 0);
      __syncthreads();          // protect smB before next-phase overwrite
    }

    if (isPG) {     // colmax(acc + b2) -> pg[rowTile*256 + ph*128 + 0..127]
      const int colBase = ph * 128;
      float m4[4] = {-1e30f, -1e30f, -1e30f, -1e30f};
#pragma unroll
      for (int j = 0; j < 4; ++j) {
        const float ex = b2[colBase + wn * 64 + j * 16 + fm];
#pragma unroll
        for (int i = 0; i < 4; ++i)
#pragma unroll
          for (int r = 0; r < 4; ++r) m4[j] = fmaxf(m4[j], acc[i][j][r] + ex);
        m4[j] = fmaxf(m4[j], __shfl_xor(m4[j], 16));
        m4[j] = fmaxf(m4[j], __shfl_xor(m4[j], 32));
      }
      const float sel = (fq == 0) ? m4[0] : (fq == 1) ? m4[1] : (fq == 2) ? m4[2] : m4[3];
      lmax[wm][wn * 64 + fq * 16 + fm] = sel;
      __syncthreads();
      if (tid < 128) {
        const float v = fmaxf(lmax[0][tid], lmax[1][tid]);
        pg[(size_t)rowTile * 256 + colBase + tid] = v;
      }
    } else {        // h46 = acc + vecb (direct scalar stores, proven epilogue)
      const int colBase = (pair - 1) * 256 + ph * 128;
#pragma unroll
      for (int j = 0; j < 4; ++j) {
        const int col = colBase + wn * 64 + j * 16 + fm;
        const float ex = vecb[col];
#pragma unroll
        for (int i = 0; i < 4; ++i) {
          const size_t row0 = rowBase + wm * 64 + i * 16 + fq * 4;
#pragma unroll
          for (int r = 0; r < 4; ++r) {
            h46[(row0 + r) * 512 + col] = f2bf_bits(acc[i][j][r] + ex);
          }
        }
      }
    }
  }
}

// =====================================================================================
// GEMM4 (8-phase): colmax(h46 @ w4^T) -> pmax. 256x256 tile, BK=64, 512 thr (8 waves,
// 2Mx4N), double-buffered 128 KiB dynamic LDS, counted vmcnt (2 at ph4/ph8, never 0
// mid-loop), st-swizzle via pre-swizzled global src + swizzled ds_read, setprio.
// R1/R5 MAPPING (proven 73.2us): banded over ALL 512 rowTiles, inline cnt skip,
// early-exit without writes (final_kernel is cnt-bounded).
// =====================================================================================
#define G4_BAR() __builtin_amdgcn_s_barrier()
#define G4_LGKM0() asm volatile("s_waitcnt lgkmcnt(0)" ::: "memory")
#define G4_LGKM8() asm volatile("s_waitcnt lgkmcnt(8)" ::: "memory")
#define G4_VM2() asm volatile("s_waitcnt vmcnt(2)" ::: "memory")
#define G4_VM0() asm volatile("s_waitcnt vmcnt(0)" ::: "memory")
#define G4_PRIO1() __builtin_amdgcn_s_setprio(1)
#define G4_PRIO0() __builtin_amdgcn_s_setprio(0)

#define G4_STG(bufi, h4, kt) do { \
  const char* _s = (((h4) < 2) ? srcA : srcB) + (size_t)((h4) & 1) * (128 * 1024) + (size_t)(kt) * 128; \
  char* _d = stDst + (bufi) * 65536 + ((h4) >> 1) * 32768 + ((h4) & 1) * 16384; \
  async_cp16(_s, _d); \
  async_cp16(_s + 64 * 1024, _d + 8192); \
} while (0)

#define G4_LDA(bufi, mh) do { \
  const char* _p = rdA + (bufi) * 65536 + (mh) * 8192; \
  af[0][0] = *(const bf16x8*)(_p + c0);        af[0][1] = *(const bf16x8*)(_p + c1); \
  af[1][0] = *(const bf16x8*)(_p + 2048 + c0); af[1][1] = *(const bf16x8*)(_p + 2048 + c1); \
  af[2][0] = *(const bf16x8*)(_p + 4096 + c0); af[2][1] = *(const bf16x8*)(_p + 4096 + c1); \
  af[3][0] = *(const bf16x8*)(_p + 6144 + c0); af[3][1] = *(const bf16x8*)(_p + 6144 + c1); \
} while (0)

#define G4_LDB(bufi, nh, bgx) do { \
  const char* _p = rdB + (bufi) * 65536 + (nh) * 4096; \
  bgx[0][0] = *(const bf16x8*)(_p + c0);        bgx[0][1] = *(const bf16x8*)(_p + c1); \
  bgx[1][0] = *(const bf16x8*)(_p + 2048 + c0); bgx[1][1] = *(const bf16x8*)(_p + 2048 + c1); \
} while (0)

#define G4_QUAD(mh, nh, bgx) do { \
  _Pragma("unroll") \
  for (int _m = 0; _m < 4; ++_m) { \
    _Pragma("unroll") \
    for (int _n = 0; _n < 2; ++_n) { \
      acc[(mh) * 4 + _m][(nh) * 2 + _n] = __builtin_amdgcn_mfma_f32_16x16x32_bf16( \
          af[_m][0], bgx[_n][0], acc[(mh) * 4 + _m][(nh) * 2 + _n], 0, 0, 0); \
      acc[(mh) * 4 + _m][(nh) * 2 + _n] = __builtin_amdgcn_mfma_f32_16x16x32_bf16( \
          af[_m][1], bgx[_n][1], acc[(mh) * 4 + _m][(nh) * 2 + _n], 0, 0, 0); \
    } \
  } \
} while (0)

__global__ __launch_bounds__(512, 2) void gemm4_8ph(
    const unsigned short* __restrict__ A, const unsigned short* __restrict__ Bw,
    float* __restrict__ outp2, const int* __restrict__ cnt) {
  extern __shared__ char sm[];   // 128 KiB: buf{0,1} x (A 32K | B 32K)

  const int gid = blockIdx.x;
  const int xcd = gid & 7;
  const int slot = gid >> 3;
  const int rowTile = xcd * 64 + (slot >> 2);   // 512 rowTiles, banded per XCD
  const int colTile = slot & 3;
  const size_t rowBase = (size_t)rowTile * 256;
  const int colBase = colTile * 256;

  const int cntb = cnt[rowBase >> 12];
  const int rb = (int)(rowBase & 4095);
  if (rb >= cntb) return;                       // final_kernel is cnt-bounded

  const int tid = threadIdx.x;
  const int lane = tid & 63;
  const int w = tid >> 6;
  const int wm = w >> 2, wn = w & 3;

  // ---- staging addressing: LDS linear dest, global source pre-swizzled ----
  const int rr = tid >> 3;                            // 0..63: row within half (j=0)
  const int csw = ((tid & 7) ^ (rr & 7)) << 4;        // swizzled 16B chunk in 128B row
  const char* srcA = (const char*)A + (rowBase + (size_t)rr) * 1024 + csw;
  const char* srcB = (const char*)Bw + ((size_t)colBase + (size_t)rr) * 1024 + csw;
  char* stDst = sm + w * 1024;                        // wave-uniform; HW adds lane*16

  // ---- read addressing (swizzled ds_read) ----
  const int fr = lane & 15, fq = lane >> 4;
  const int c0 = (fq * 16) ^ ((lane & 7) << 4);
  const int c1 = ((fq * 16) | 64) ^ ((lane & 7) << 4);
  const char* rdA = sm + (wm * 128 + fr) * 128;       // + buf*65536 + mh*8192 + m*2048
  const char* rdB = sm + 32768 + (wn * 64 + fr) * 128;

  floatx4 acc[8][4];
  const floatx4 zero = {0.f, 0.f, 0.f, 0.f};
#pragma unroll
  for (int i = 0; i < 8; ++i)
#pragma unroll
    for (int j = 0; j < 4; ++j) acc[i][j] = zero;

  bf16x8 af[4][2], bg0[2][2], bg1[2][2];

  // prologue: tile0 fully -> buf0; tile1.h0 -> buf1; wait tile0 (leave 2 in flight)
  G4_STG(0, 0, 0); G4_STG(0, 1, 0); G4_STG(0, 2, 0); G4_STG(0, 3, 0);
  G4_STG(1, 0, 1);
  G4_VM2(); G4_BAR();

  for (int it = 0; it < 3; ++it) {
    const int tO = 2 * it + 1, tE2 = 2 * it + 2, tO2 = 2 * it + 3;
    // ph1: E quad(0,0)
    G4_LDA(0, 0); G4_LDB(0, 0, bg0); G4_STG(1, 1, tO); G4_LGKM8(); G4_BAR(); G4_LGKM0();
    G4_PRIO1(); G4_QUAD(0, 0, bg0); G4_PRIO0(); G4_BAR();
    // ph2: E quad(0,1)
    G4_LDB(0, 1, bg1); G4_STG(1, 2, tO); G4_BAR(); G4_LGKM0();
    G4_PRIO1(); G4_QUAD(0, 1, bg1); G4_PRIO0(); G4_BAR();
    // ph3: E quad(1,1)
    G4_LDA(0, 1); G4_STG(1, 3, tO); G4_BAR(); G4_LGKM0();
    G4_PRIO1(); G4_QUAD(1, 1, bg1); G4_PRIO0(); G4_BAR();
    // ph4: E quad(1,0)  [regs only; buf0 free -> start tE2; wait O tile landed]
    G4_STG(0, 0, tE2); G4_VM2(); G4_BAR();
    G4_PRIO1(); G4_QUAD(1, 0, bg0); G4_PRIO0(); G4_BAR();
    // ph5: O quad(0,0)
    G4_LDA(1, 0); G4_LDB(1, 0, bg0); G4_STG(0, 1, tE2); G4_LGKM8(); G4_BAR(); G4_LGKM0();
    G4_PRIO1(); G4_QUAD(0, 0, bg0); G4_PRIO0(); G4_BAR();
    // ph6: O quad(0,1)
    G4_LDB(1, 1, bg1); G4_STG(0, 2, tE2); G4_BAR(); G4_LGKM0();
    G4_PRIO1(); G4_QUAD(0, 1, bg1); G4_PRIO0(); G4_BAR();
    // ph7: O quad(1,1)
    G4_LDA(1, 1); G4_STG(0, 3, tE2); G4_BAR(); G4_LGKM0();
    G4_PRIO1(); G4_QUAD(1, 1, bg1); G4_PRIO0(); G4_BAR();
    // ph8: O quad(1,0)  [buf1 free -> start tO2; wait tE2 landed]
    G4_STG(1, 0, tO2); G4_VM2(); G4_BAR();
    G4_PRIO1(); G4_QUAD(1, 0, bg0); G4_PRIO0(); G4_BAR();
  }

  // drain iteration: tiles 6 (buf0) and 7 (buf1)
  G4_LDA(0, 0); G4_LDB(0, 0, bg0); G4_STG(1, 1, 7); G4_LGKM8(); G4_BAR(); G4_LGKM0();
  G4_PRIO1(); G4_QUAD(0, 0, bg0); G4_PRIO0(); G4_BAR();
  G4_LDB(0, 1, bg1); G4_STG(1, 2, 7); G4_BAR(); G4_LGKM0();
  G4_PRIO1(); G4_QUAD(0, 1, bg1); G4_PRIO0(); G4_BAR();
  G4_LDA(0, 1); G4_STG(1, 3, 7); G4_BAR(); G4_LGKM0();
  G4_PRIO1(); G4_QUAD(1, 1, bg1); G4_PRIO0(); G4_BAR();
  G4_VM0(); G4_BAR();
  G4_PRIO1(); G4_QUAD(1, 0, bg0); G4_PRIO0(); G4_BAR();
  G4_LDA(1, 0); G4_LDB(1, 0, bg0); G4_BAR(); G4_LGKM0();
  G4_PRIO1(); G4_QUAD(0, 0, bg0); G4_PRIO0(); G4_BAR();
  G4_LDB(1, 1, bg1); G4_BAR(); G4_LGKM0();
  G4_PRIO1(); G4_QUAD(0, 1, bg1); G4_PRIO0(); G4_BAR();
  G4_LDA(1, 1); G4_BAR(); G4_LGKM0();
  G4_PRIO1(); G4_QUAD(1, 1, bg1); G4_PRIO0(); G4_BAR();
  G4_PRIO1(); G4_QUAD(1, 0, bg0); G4_PRIO0(); G4_BAR();

  // ---- colmax epilogue (reuse LDS as float scratch; all buffer reads done) ----
  float* smf = (float*)sm;
  float mv[4];
#pragma unroll
  for (int nj = 0; nj < 4; ++nj) {
    float m = -1e30f;
#pragma unroll
    for (int mi = 0; mi < 8; ++mi)
#pragma unroll
      for (int r = 0; r < 4; ++r) m = fmaxf(m, acc[mi][nj][r]);
    m = fmaxf(m, __shfl_xor(m, 16));
    m = fmaxf(m, __shfl_xor(m, 32));
    mv[nj] = m;
  }
  const float sel = (fq == 0) ? mv[0] : (fq == 1) ? mv[1] : (fq == 2) ? mv[2] : mv[3];
  smf[wm * 256 + wn * 64 + fq * 16 + fr] = sel;
  __syncthreads();
  if (tid < 256) {
    outp2[(size_t)rowTile * 1024 + colBase + tid] = fmaxf(smf[tid], smf[256 + tid]);
  }
}

// =====================================================================================
// Fused gmax reduce + cvec, COALESCED GEMV. 128 blocks (4/batch). Per block:
// gm[t] = max over only the ceil(cnt/128) real pg slots, with b2 baseline (invisible
// rows contribute exactly b2); then wave-per-row dot: lane holds w3[p][lane*4..+4]
// (float4, coalesced) x gm (from LDS), shuffle-reduce over 64.
// =====================================================================================
__global__ __launch_bounds__(256) void gmax_cvec_kernel(
    const float* __restrict__ pg, const float* __restrict__ w3,
    float* __restrict__ cvec, const int* __restrict__ cnt,
    const float* __restrict__ b2) {
  __shared__ float gm[256];
  const int b = blockIdx.x >> 2, quarter = blockIdx.x & 3;
  const int t = threadIdx.x;
  const int c = cnt[b];
  const int nt = (c + 127) >> 7;
  float m = (c < 4096) ? b2[t] : -1e30f;
  for (int s = 0; s < nt; ++s) m = fmaxf(m, pg[((size_t)b * 32 + s) * 256 + t]);
  gm[t] = m;
  __syncthreads();
  const int lane = t & 63, wv = t >> 6;
  const float g0 = gm[lane * 4 + 0];
  const float g1 = gm[lane * 4 + 1];
  const float g2v = gm[lane * 4 + 2];
  const float g3 = gm[lane * 4 + 3];
  for (int pp = 0; pp < 32; ++pp) {
    const int p = quarter * 128 + wv * 32 + pp;
    const float4 wr = *(const float4*)(w3 + (size_t)p * 512 + lane * 4);
    float s = wr.x * g0 + wr.y * g1 + wr.z * g2v + wr.w * g3;
    for (int o = 32; o; o >>= 1) s += __shfl_xor(s, o);
    if (lane == 0) cvec[b * 512 + p] = s;
  }
}

// =====================================================================================
// K_h: (+cvec) + LayerNorm(512) + relu in place on h46 (compacted).  R1-proven
// 32768-block version: rows < cnt: LN+relu; rows [cnt, ceil256): zero (gemm4 reads
// 256-row tiles); rows >= ceil256: untouched (no readers).
// =====================================================================================
__global__ __launch_bounds__(256) void ln2_kernel(
    unsigned short* __restrict__ h46, const int* __restrict__ cnt,
    const float* __restrict__ cvec,
    const float* __restrict__ g2, const float* __restrict__ be2) {
  const int lane = threadIdx.x & 63;
  const int wv = threadIdx.x >> 6;
  const size_t p = (size_t)blockIdx.x * 4 + wv;
  const int cb = cnt[p >> 12];
  const int pin = (int)(p & 4095);
  const int ceilv = (cb + 255) & ~255;
  if (pin >= ceilv) return;
  unsigned short* row = h46 + p * 512;
  const int c0 = lane * 8;
  if (pin >= cb) {                            // straddle zero-fill
    const uint4 z = {0, 0, 0, 0};
    *(uint4*)(row + c0) = z;
    return;
  }
  const int b = (int)(p >> 12);
  union { uint4 v; unsigned short s[8]; } in;
  in.v = *(const uint4*)(row + c0);
  float cv[8];
  *(float4*)(cv) = *(const float4*)(cvec + b * 512 + c0);
  *(float4*)(cv + 4) = *(const float4*)(cvec + b * 512 + c0 + 4);
  float f[8];
  float s = 0.f;
#pragma unroll
  for (int k = 0; k < 8; ++k) { f[k] = bf2f(in.s[k]) + cv[k]; s += f[k]; }
  for (int o = 32; o; o >>= 1) s += __shfl_xor(s, o);
  const float mu = s * (1.f / 512.f);
  float q = 0.f;
#pragma unroll
  for (int k = 0; k < 8; ++k) { const float d = f[k] - mu; q += d * d; }
  for (int o = 32; o; o >>= 1) q += __shfl_xor(q, o);
  const float rs = rsqrtf(q * (1.f / 512.f) + LN_EPS);
  union { uint4 v; unsigned short s[8]; } outv;
#pragma unroll
  for (int k = 0; k < 8; ++k) {
    const float y = fmaxf((f[k] - mu) * rs * g2[c0 + k] + be2[c0 + k], 0.f);
    outv.s[k] = f2bf_bits(y);
  }
  *(uint4*)(row + c0) = outv.v;
}

// =====================================================================================
// K_j: out[b][f] = max over the ceil(cnt/256) real pmax tiles, with 0 baseline when
// any row is invisible (h7 = 0 there), + b4[f].
// =====================================================================================
__global__ __launch_bounds__(256) void final_kernel(
    const float* __restrict__ pmax, const float* __restrict__ b4,
    float* __restrict__ out, const int* __restrict__ cnt) {
  const int idx = blockIdx.x * 256 + threadIdx.x;
  const int b = idx >> 10, f = idx & 1023;
  const int c = cnt[b];
  const int nt = (c + 255) >> 8;
  float m = (c < 4096) ? 0.f : -1e30f;
  for (int r = 0; r < nt; ++r) m = fmaxf(m, pmax[((size_t)(b * 16 + r)) * 1024 + f]);
  out[idx] = m + b4[f];
}

// =====================================================================================
extern "C" void kernel_launch(void* const* d_in, const int* in_sizes, int n_in,
                              void* d_out, int out_size, void* d_ws, size_t ws_size,
                              hipStream_t stream) {
  const float* points = (const float*)d_in[0];
  const int* mask = (const int*)d_in[1];
  const float* w1 = (const float*)d_in[2];
  const float* g1 = (const float*)d_in[3];
  const float* be1 = (const float*)d_in[4];
  const float* w2 = (const float*)d_in[5];
  const float* b2 = (const float*)d_in[6];
  const float* w3 = (const float*)d_in[7];
  const float* g2 = (const float*)d_in[8];
  const float* be2 = (const float*)d_in[9];
  const float* w4 = (const float*)d_in[10];
  const float* b4 = (const float*)d_in[11];
  float* out = (float*)d_out;
  char* ws = (char*)d_ws;

  const size_t OFF_H46 = 0;                          // 134217728 B (bf16 131072x512)
  const size_t OFF_H2 = 134217728;                   //  33554432 B (bf16 131072x128)
  const size_t OFF_W2B = OFF_H2 + 33554432;          //     65536 B
  const size_t OFF_W4B = OFF_W2B + 65536;            //   1048576 B
  const size_t OFF_W23B = OFF_W4B + 1048576;         //    131072 B (bf16 512x128)
  const size_t OFF_VECB = OFF_W23B + 131072;         //      2048 B (f32 512)
  const size_t OFF_PG = OFF_VECB + 2048;             //   1048576 B (f32 1024x256)
  const size_t OFF_CVEC = OFF_PG + 1048576;          //     65536 B
  const size_t OFF_PMAX = OFF_CVEC + 65536;          //   4194304 B (uses 2 MB)
  const size_t OFF_CNT = OFF_PMAX + 4194304;         //      4096 B
  const size_t OFF_NEWROW = OFF_CNT + 4096;          //    524288 B (~174 MB total)

  unsigned short* h2 = (unsigned short*)(ws + OFF_H2);
  unsigned short* h46 = (unsigned short*)(ws + OFF_H46);
  unsigned short* w2b = (unsigned short*)(ws + OFF_W2B);
  unsigned short* w4b = (unsigned short*)(ws + OFF_W4B);
  unsigned short* w23b = (unsigned short*)(ws + OFF_W23B);
  float* vecb = (float*)(ws + OFF_VECB);
  float* pg = (float*)(ws + OFF_PG);
  float* cvecp = (float*)(ws + OFF_CVEC);
  float* pmaxp = (float*)(ws + OFF_PMAX);
  int* cntp = (int*)(ws + OFF_CNT);
  int* newrow = (int*)(ws + OFF_NEWROW);

  // one-time: allow 128 KiB dynamic LDS for the 8-phase GEMM (host config, not a
  // stream op -- graph-capture safe)
  static bool s_attr_done = false;
  if (!s_attr_done) {
    hipFuncSetAttribute((const void*)gemm4_8ph,
                        hipFuncAttributeMaxDynamicSharedMemorySize, 131072);
    s_attr_done = true;
  }

  // 0. visible-first compaction map per batch
  perm_kernel<<<32, 256, 0, stream>>>(mask, newrow, cntp);
  // 1. conv1+LN1+relu -> h2 (64-lane, proven); tails: wconv + W23/vecb precompute
  conv1_ln_kernel<<<32768 + 2176 + 256, 256, 0, stream>>>(
      points, w1, g1, be1, h2, newrow, cntp, w2, b2, w3, w4, w2b, w4b, w23b, vecb);
  // 2. fused A-resident PAIRED: pg = colmax(h2@w2^T + b2) AND h46 = h2@W23^T + vecb
  gemm23_fused<<<3072, 256, 0, stream>>>(h2, w2b, w23b, h46, pg, b2, vecb, cntp);
  // 3. gmax + cvec (coalesced GEMV, 128 blocks, cnt-bounded with b2 baseline)
  gmax_cvec_kernel<<<128, 256, 0, stream>>>(pg, w3, cvecp, cntp, b2);
  // 4. (+cvec) + LN2 + relu in place; zero straddle rows [cnt, ceil256)
  ln2_kernel<<<32768, 256, 0, stream>>>(h46, cntp, cvecp, g2, be2);
  // 5. h7 colmax -> pmax, 256x256 8-phase (R1/R5 proven mapping)
  gemm4_8ph<<<2048, 512, 131072, stream>>>(h46, w4b, pmaxp, cntp);
  // 6. out = max over real row-blocks + b4 (0 baseline for invisible rows)
  final_kernel<<<128, 256, 0, stream>>>(pmaxp, b4, out, cntp);
}

// Round 9
// 267.154 us; speedup vs baseline: 1.5406x; 1.0130x over previous
//
#include <hip/hip_runtime.h>
#include <stdint.h>

#define LN_EPS 1e-5f

// ---------- bf16 helpers (RNE, bit-level) ----------
static __device__ __forceinline__ unsigned short f2bf_bits(float f) {
  union { float f; unsigned u; } v; v.f = f;
  unsigned r = v.u + 0x7FFFu + ((v.u >> 16) & 1u);
  return (unsigned short)(r >> 16);
}
static __device__ __forceinline__ float bf2f(unsigned short h) {
  union { unsigned u; float f; } v; v.u = ((unsigned)h) << 16;
  return v.f;
}

typedef __bf16 bf16x8 __attribute__((ext_vector_type(8)));
typedef float floatx4 __attribute__((ext_vector_type(4)));

// ---------- async global->LDS, 16B per lane ----------
typedef __attribute__((address_space(1))) unsigned int* gas_ptr;
typedef __attribute__((address_space(3))) unsigned int* las_ptr;
static __device__ __forceinline__ void async_cp16(const void* g, void* l) {
  __builtin_amdgcn_global_load_lds((gas_ptr)g, (las_ptr)l, 16, 0, 0);
}

// =====================================================================================
// perm: per batch, stable partition visible-first. newrow[b*4096+n] = within-batch
// destination row; cnt[b] = #visible. Block 32: precompute closed-form LN1 params
// from w1: lnp[0..2] = wbar (mean row), lnp[3..8] = M = mean_c (w1[c]-wbar) outer
// products {00,11,22,01,02,12}. (LN of a linear map: mu = wbar.x, var = x^T M x.)
// =====================================================================================
__global__ __launch_bounds__(256) void perm_kernel(
    const int* __restrict__ mask, int* __restrict__ newrow, int* __restrict__ cnt,
    const float* __restrict__ w1, float* __restrict__ lnp) {
  if (blockIdx.x >= 32) {        // LN1-param block
    __shared__ float part[2][6];
    __shared__ float wb[3];
    const int t = threadIdx.x;
    const int lane = t & 63, wv = t >> 6;
    float v0 = 0.f, v1 = 0.f, v2 = 0.f;
    if (t < 128) { v0 = w1[t * 3]; v1 = w1[t * 3 + 1]; v2 = w1[t * 3 + 2]; }
    if (wv < 2) {
      float s0 = v0, s1 = v1, s2 = v2;
      for (int o = 32; o; o >>= 1) {
        s0 += __shfl_xor(s0, o); s1 += __shfl_xor(s1, o); s2 += __shfl_xor(s2, o);
      }
      if (lane == 0) { part[wv][0] = s0; part[wv][1] = s1; part[wv][2] = s2; }
    }
    __syncthreads();
    if (t == 0) {
      wb[0] = (part[0][0] + part[1][0]) * (1.f / 128.f);
      wb[1] = (part[0][1] + part[1][1]) * (1.f / 128.f);
      wb[2] = (part[0][2] + part[1][2]) * (1.f / 128.f);
    }
    __syncthreads();
    float m00 = 0.f, m11 = 0.f, m22 = 0.f, m01 = 0.f, m02 = 0.f, m12 = 0.f;
    if (t < 128) {
      const float d0 = v0 - wb[0], d1 = v1 - wb[1], d2 = v2 - wb[2];
      m00 = d0 * d0; m11 = d1 * d1; m22 = d2 * d2;
      m01 = d0 * d1; m02 = d0 * d2; m12 = d1 * d2;
    }
    if (wv < 2) {
      for (int o = 32; o; o >>= 1) {
        m00 += __shfl_xor(m00, o); m11 += __shfl_xor(m11, o); m22 += __shfl_xor(m22, o);
        m01 += __shfl_xor(m01, o); m02 += __shfl_xor(m02, o); m12 += __shfl_xor(m12, o);
      }
      if (lane == 0) {
        part[wv][0] = m00; part[wv][1] = m11; part[wv][2] = m22;
        part[wv][3] = m01; part[wv][4] = m02; part[wv][5] = m12;
      }
    }
    __syncthreads();
    if (t == 0) {
      lnp[0] = wb[0]; lnp[1] = wb[1]; lnp[2] = wb[2];
      lnp[3] = (part[0][0] + part[1][0]) * (1.f / 128.f);
      lnp[4] = (part[0][1] + part[1][1]) * (1.f / 128.f);
      lnp[5] = (part[0][2] + part[1][2]) * (1.f / 128.f);
      lnp[6] = (part[0][3] + part[1][3]) * (1.f / 128.f);
      lnp[7] = (part[0][4] + part[1][4]) * (1.f / 128.f);
      lnp[8] = (part[0][5] + part[1][5]) * (1.f / 128.f);
    }
    return;
  }
  const int b = blockIdx.x, t = threadIdx.x;
  const int base = b * 4096 + t * 16;
  int v[16]; int s = 0;
#pragma unroll
  for (int i = 0; i < 16; ++i) { v[i] = (mask[base + i] != 0); s += v[i]; }
  const int lane = t & 63, wv = t >> 6;
  int scan = s;
  for (int o = 1; o < 64; o <<= 1) { int x = __shfl_up(scan, o); if (lane >= o) scan += x; }
  __shared__ int wsum[4], woff[4], stotal;
  if (lane == 63) wsum[wv] = scan;
  __syncthreads();
  if (t == 0) { int a = 0; for (int k = 0; k < 4; ++k) { woff[k] = a; a += wsum[k]; } stotal = a; cnt[b] = a; }
  __syncthreads();
  const int excl = scan - s + woff[wv];
  const int total = stotal;
  int run = 0;
#pragma unroll
  for (int i = 0; i < 16; ++i) {
    const int pos = t * 16 + i;
    const int visBefore = excl + run;
    newrow[b * 4096 + pos] = v[i] ? visBefore : total + (pos - visBefore);
    run += v[i];
  }
}

// =====================================================================================
// K_b: conv1 (K=3, fp32 exact) + CLOSED-FORM LayerNorm(128) + mask + relu -> h2 bf16,
// compacted scatter via newrow. LN stats from lnp (mu = wbar.x, var = x^T M x) --
// no cross-lane reductions (removes 2x6 serial shuffle chains).
// Block tail 1 [32768, 32768+2176): fp32->bf16 for w2, w4.
// Block tail 2 [34944, 34944+256): W23 = w3R@w2 (fp32, ->bf16) and vecb = w3R@b2.
// =====================================================================================
__global__ __launch_bounds__(256) void conv1_ln_kernel(
    const float* __restrict__ points,
    const float* __restrict__ w1, const float* __restrict__ g1,
    const float* __restrict__ be1, unsigned short* __restrict__ h2,
    const int* __restrict__ newrow, const int* __restrict__ cnt,
    const float* __restrict__ w2, const float* __restrict__ b2,
    const float* __restrict__ w3, const float* __restrict__ w4,
    unsigned short* __restrict__ w2b, unsigned short* __restrict__ w4b,
    unsigned short* __restrict__ w23b, float* __restrict__ vecb,
    const float* __restrict__ lnp) {
  if (blockIdx.x >= 32768) {
    const int bb = blockIdx.x - 32768;
    if (bb < 2176) {              // wconv: w2 (32768) + w4 (524288)
      int idx = bb * 256 + threadIdx.x;
      if (idx < 32768) w2b[idx] = f2bf_bits(w2[idx]);
      else w4b[idx - 32768] = f2bf_bits(w4[idx - 32768]);
    } else {                      // W23 = w3[:,256:] @ w2  [512x128], 2 rows per block
      const int tid = threadIdx.x;
      const int p = (bb - 2176) * 2 + (tid >> 7);
      const int c = tid & 127;
      const float* w3r = w3 + (size_t)p * 512 + 256;
      float s = 0.f;
      for (int k = 0; k < 256; ++k) s += w3r[k] * w2[k * 128 + c];
      w23b[p * 128 + c] = f2bf_bits(s);
      if (c == 0) {
        float vb = 0.f;
        for (int k = 0; k < 256; ++k) vb += w3r[k] * b2[k];
        vecb[p] = vb;
      }
    }
    return;
  }
  const int lane = threadIdx.x & 63;
  const int wv = threadIdx.x >> 6;
  const size_t p = (size_t)blockIdx.x * 4 + wv;
  const int dest = newrow[p];
  const int cntb = cnt[p >> 12];
  const int ceilv = (cntb + 127) & ~127;
  if (dest >= ceilv) return;                 // row never read downstream
  const bool vis = (dest < cntb);
  const float x0 = points[p * 3 + 0];
  const float x1 = points[p * 3 + 1];
  const float x2 = points[p * 3 + 2];
  // closed-form LN stats (no cross-lane reduction)
  const float mu = lnp[0] * x0 + lnp[1] * x1 + lnp[2] * x2;
  const float q  = lnp[3] * x0 * x0 + lnp[4] * x1 * x1 + lnp[5] * x2 * x2
                 + 2.f * (lnp[6] * x0 * x1 + lnp[7] * x0 * x2 + lnp[8] * x1 * x2);
  const float rs = rsqrtf(q + LN_EPS);
  const int c0 = lane * 2, c1 = c0 + 1;
  const float h00 = w1[c0 * 3] * x0 + w1[c0 * 3 + 1] * x1 + w1[c0 * 3 + 2] * x2;
  const float h01 = w1[c1 * 3] * x0 + w1[c1 * 3 + 1] * x1 + w1[c1 * 3 + 2] * x2;
  const float y0 = vis ? fmaxf((h00 - mu) * rs * g1[c0] + be1[c0], 0.f) : 0.f;
  const float y1 = vis ? fmaxf((h01 - mu) * rs * g1[c1] + be1[c1], 0.f) : 0.f;
  union { unsigned u; unsigned short s2[2]; } pk;
  pk.s2[0] = f2bf_bits(y0);
  pk.s2[1] = f2bf_bits(y1);
  const size_t prow = (p & ~(size_t)4095) + (size_t)dest;
  ((unsigned*)h2)[prow * 64 + lane] = pk.u;
}

// =====================================================================================
// gemm23_fused (A-RESIDENT PAIRED): A = h2 [M x 128] staged ONCE per block into a
// resident 32KB 4-panel LDS region; each block processes ONE rowTile x ONE colTile
// PAIR: pair0 = PG cols {0,128} (Bw=w2b, colmax(+b2) -> pg), pair1 = OUT cols {0,128},
// pair2 = OUT cols {256,384} (Bw=w23b, h46 = h2@W23^T + vecb). Grid 3072, XCD-banded
// (xcd = gid&7, rowTile = xcd*128 + slot/3, pair = slot%3). Inner loop per phase is
// byte-identical MFMA order to the proven R1 kernel (numerics unchanged). Skip tiles
// (rb >= cnt) exit without writes (gmax/final are cnt-bounded).
// LDS: 32KB A + 16KB B + 1KB lmax = 49KB -> 3 blocks/CU (12 waves).
// =====================================================================================
__global__ __launch_bounds__(256) void gemm23_fused(
    const unsigned short* __restrict__ A,
    const unsigned short* __restrict__ w2b, const unsigned short* __restrict__ w23b,
    unsigned short* __restrict__ h46, float* __restrict__ pg,
    const float* __restrict__ b2, const float* __restrict__ vecb,
    const int* __restrict__ cnt) {
  __shared__ __align__(16) char smA[4][128 * 64];   // resident A, K quarters (8KB ea)
  __shared__ __align__(16) char smB[2][128 * 64];   // B twin panels per k-step
  __shared__ float lmax[2][128];

  const int gid = blockIdx.x;
  const int xcd = gid & 7;
  const int slot = gid >> 3;                  // 0..383
  const int rowTile = xcd * 128 + slot / 3;   // 1024 rowTiles, banded per XCD
  const int pair = slot - (slot / 3) * 3;     // 0=PG{0,128}, 1=OUT{0,128}, 2=OUT{256,384}
  const size_t rowBase = (size_t)rowTile * 128;

  const int cntb = cnt[rowBase >> 12];
  const int rb = (int)(rowBase & 4095);
  if (rb >= cntb) return;                     // downstream readers are cnt-bounded

  const int tid = threadIdx.x;
  const int lane = tid & 63;
  const int w = tid >> 6;
  const int wm = w >> 1, wn = w & 1;

  const bool isPG = (pair == 0);
  const unsigned short* Bw = isPG ? w2b : w23b;

  const int rSub = lane >> 2;
  const int cb16 = (lane & 3) * 16;
  const size_t skip16 = 16 * 256;             // 16 rows x 256 B/row

  // ---- prologue: stage full-K A panel (8 x cp16/thread), resident for both phases --
  const char* gA = (const char*)A + (rowBase + (size_t)(w * 32 + rSub)) * 256 + cb16;
#pragma unroll
  for (int q = 0; q < 4; ++q) {
    async_cp16(gA + q * 64, smA[q] + w * 2048);
    async_cp16(gA + q * 64 + skip16, smA[q] + w * 2048 + 1024);
  }

  char* lB0 = smB[0] + w * 2048;
  char* lB1 = smB[1] + w * 2048;

  const int fm = lane & 15, fq = lane >> 4;
  const int fOff = fm * 64 + fq * 16;
  const char* pb0 = smB[0] + wn * 64 * 64 + fOff;
  const char* pb1 = smB[1] + wn * 64 * 64 + fOff;

  const floatx4 zero = {0.f, 0.f, 0.f, 0.f};

  for (int ph = 0; ph < 2; ++ph) {
    const int bRow = isPG ? ph * 128 : ((pair - 1) * 256 + ph * 128);
    floatx4 acc[4][4];
#pragma unroll
    for (int i = 0; i < 4; ++i)
#pragma unroll
      for (int j = 0; j < 4; ++j) acc[i][j] = zero;

    const char* gB = (const char*)Bw + ((size_t)(bRow + w * 32 + rSub)) * 256 + cb16;

    for (int k0i = 0; k0i < 2; ++k0i) {
      async_cp16(gB, lB0);
      async_cp16(gB + skip16, lB0 + 1024);
      async_cp16(gB + 64, lB1);
      async_cp16(gB + 64 + skip16, lB1 + 1024);
      gB += 128;
      __syncthreads();          // compiler drains vmcnt before barrier: A+B staged
      const char* pa0 = smA[2 * k0i] + wm * 64 * 64 + fOff;
      const char* pa1 = smA[2 * k0i + 1] + wm * 64 * 64 + fOff;
      bf16x8 af0[4], bg0[4], af1[4], bg1[4];
#pragma unroll
      for (int i = 0; i < 4; ++i) af0[i] = *(const bf16x8*)(pa0 + i * 16 * 64);
#pragma unroll
      for (int j = 0; j < 4; ++j) bg0[j] = *(const bf16x8*)(pb0 + j * 16 * 64);
#pragma unroll
      for (int i = 0; i < 4; ++i)
#pragma unroll
        for (int j = 0; j < 4; ++j)
          acc[i][j] = __builtin_amdgcn_mfma_f32_16x16x32_bf16(af0[i], bg0[j], acc[i][j], 0, 0, 0);
#pragma unroll
      for (int i = 0; i < 4; ++i) af1[i] = *(const bf16x8*)(pa1 + i * 16 * 64);
#pragma unroll
      for (int j = 0; j < 4; ++j) bg1[j] = *(const bf16x8*)(pb1 + j * 16 * 64);
#pragma unroll
      for (int i = 0; i < 4; ++i)
#pragma unroll
        for (int j = 0; j < 4; ++j)
          acc[i][j] = __builtin_amdgcn_mfma_f32_16x16x32_bf16(af1[i], bg1[j], acc[i][j], 0, 0, 0);
      __syncthreads();          // protect smB before next-phase overwrite
    }

    if (isPG) {     // colmax(acc + b2) -> pg[rowTile*256 + ph*128 + 0..127]
      const int colBase = ph * 128;
      float m4[4] = {-1e30f, -1e30f, -1e30f, -1e30f};
#pragma unroll
      for (int j = 0; j < 4; ++j) {
        const float ex = b2[colBase + wn * 64 + j * 16 + fm];
#pragma unroll
        for (int i = 0; i < 4; ++i)
#pragma unroll
          for (int r = 0; r < 4; ++r) m4[j] = fmaxf(m4[j], acc[i][j][r] + ex);
        m4[j] = fmaxf(m4[j], __shfl_xor(m4[j], 16));
        m4[j] = fmaxf(m4[j], __shfl_xor(m4[j], 32));
      }
      const float sel = (fq == 0) ? m4[0] : (fq == 1) ? m4[1] : (fq == 2) ? m4[2] : m4[3];
      lmax[wm][wn * 64 + fq * 16 + fm] = sel;
      __syncthreads();
      if (tid < 128) {
        const float v = fmaxf(lmax[0][tid], lmax[1][tid]);
        pg[(size_t)rowTile * 256 + colBase + tid] = v;
      }
    } else {        // h46 = acc + vecb (direct scalar stores, proven epilogue)
      const int colBase = (pair - 1) * 256 + ph * 128;
#pragma unroll
      for (int j = 0; j < 4; ++j) {
        const int col = colBase + wn * 64 + j * 16 + fm;
        const float ex = vecb[col];
#pragma unroll
        for (int i = 0; i < 4; ++i) {
          const size_t row0 = rowBase + wm * 64 + i * 16 + fq * 4;
#pragma unroll
          for (int r = 0; r < 4; ++r) {
            h46[(row0 + r) * 512 + col] = f2bf_bits(acc[i][j][r] + ex);
          }
        }
      }
    }
  }
}

// =====================================================================================
// GEMM4 (8-phase): colmax(h46 @ w4^T) -> pmax. 256x256 tile, BK=64, 512 thr (8 waves,
// 2Mx4N), double-buffered 128 KiB dynamic LDS, counted vmcnt (2 at ph4/ph8, never 0
// mid-loop), st-swizzle via pre-swizzled global src + swizzled ds_read, setprio.
// R1/R5 MAPPING (proven 72.2us): banded over ALL 512 rowTiles, inline cnt skip,
// early-exit without writes (final_kernel is cnt-bounded).
// =====================================================================================
#define G4_BAR() __builtin_amdgcn_s_barrier()
#define G4_LGKM0() asm volatile("s_waitcnt lgkmcnt(0)" ::: "memory")
#define G4_LGKM8() asm volatile("s_waitcnt lgkmcnt(8)" ::: "memory")
#define G4_VM2() asm volatile("s_waitcnt vmcnt(2)" ::: "memory")
#define G4_VM0() asm volatile("s_waitcnt vmcnt(0)" ::: "memory")
#define G4_PRIO1() __builtin_amdgcn_s_setprio(1)
#define G4_PRIO0() __builtin_amdgcn_s_setprio(0)

#define G4_STG(bufi, h4, kt) do { \
  const char* _s = (((h4) < 2) ? srcA : srcB) + (size_t)((h4) & 1) * (128 * 1024) + (size_t)(kt) * 128; \
  char* _d = stDst + (bufi) * 65536 + ((h4) >> 1) * 32768 + ((h4) & 1) * 16384; \
  async_cp16(_s, _d); \
  async_cp16(_s + 64 * 1024, _d + 8192); \
} while (0)

#define G4_LDA(bufi, mh) do { \
  const char* _p = rdA + (bufi) * 65536 + (mh) * 8192; \
  af[0][0] = *(const bf16x8*)(_p + c0);        af[0][1] = *(const bf16x8*)(_p + c1); \
  af[1][0] = *(const bf16x8*)(_p + 2048 + c0); af[1][1] = *(const bf16x8*)(_p + 2048 + c1); \
  af[2][0] = *(const bf16x8*)(_p + 4096 + c0); af[2][1] = *(const bf16x8*)(_p + 4096 + c1); \
  af[3][0] = *(const bf16x8*)(_p + 6144 + c0); af[3][1] = *(const bf16x8*)(_p + 6144 + c1); \
} while (0)

#define G4_LDB(bufi, nh, bgx) do { \
  const char* _p = rdB + (bufi) * 65536 + (nh) * 4096; \
  bgx[0][0] = *(const bf16x8*)(_p + c0);        bgx[0][1] = *(const bf16x8*)(_p + c1); \
  bgx[1][0] = *(const bf16x8*)(_p + 2048 + c0); bgx[1][1] = *(const bf16x8*)(_p + 2048 + c1); \
} while (0)

#define G4_QUAD(mh, nh, bgx) do { \
  _Pragma("unroll") \
  for (int _m = 0; _m < 4; ++_m) { \
    _Pragma("unroll") \
    for (int _n = 0; _n < 2; ++_n) { \
      acc[(mh) * 4 + _m][(nh) * 2 + _n] = __builtin_amdgcn_mfma_f32_16x16x32_bf16( \
          af[_m][0], bgx[_n][0], acc[(mh) * 4 + _m][(nh) * 2 + _n], 0, 0, 0); \
      acc[(mh) * 4 + _m][(nh) * 2 + _n] = __builtin_amdgcn_mfma_f32_16x16x32_bf16( \
          af[_m][1], bgx[_n][1], acc[(mh) * 4 + _m][(nh) * 2 + _n], 0, 0, 0); \
    } \
  } \
} while (0)

__global__ __launch_bounds__(512, 2) void gemm4_8ph(
    const unsigned short* __restrict__ A, const unsigned short* __restrict__ Bw,
    float* __restrict__ outp2, const int* __restrict__ cnt) {
  extern __shared__ char sm[];   // 128 KiB: buf{0,1} x (A 32K | B 32K)

  const int gid = blockIdx.x;
  const int xcd = gid & 7;
  const int slot = gid >> 3;
  const int rowTile = xcd * 64 + (slot >> 2);   // 512 rowTiles, banded per XCD
  const int colTile = slot & 3;
  const size_t rowBase = (size_t)rowTile * 256;
  const int colBase = colTile * 256;

  const int cntb = cnt[rowBase >> 12];
  const int rb = (int)(rowBase & 4095);
  if (rb >= cntb) return;                       // final_kernel is cnt-bounded

  const int tid = threadIdx.x;
  const int lane = tid & 63;
  const int w = tid >> 6;
  const int wm = w >> 2, wn = w & 3;

  // ---- staging addressing: LDS linear dest, global source pre-swizzled ----
  const int rr = tid >> 3;                            // 0..63: row within half (j=0)
  const int csw = ((tid & 7) ^ (rr & 7)) << 4;        // swizzled 16B chunk in 128B row
  const char* srcA = (const char*)A + (rowBase + (size_t)rr) * 1024 + csw;
  const char* srcB = (const char*)Bw + ((size_t)colBase + (size_t)rr) * 1024 + csw;
  char* stDst = sm + w * 1024;                        // wave-uniform; HW adds lane*16

  // ---- read addressing (swizzled ds_read) ----
  const int fr = lane & 15, fq = lane >> 4;
  const int c0 = (fq * 16) ^ ((lane & 7) << 4);
  const int c1 = ((fq * 16) | 64) ^ ((lane & 7) << 4);
  const char* rdA = sm + (wm * 128 + fr) * 128;       // + buf*65536 + mh*8192 + m*2048
  const char* rdB = sm + 32768 + (wn * 64 + fr) * 128;

  floatx4 acc[8][4];
  const floatx4 zero = {0.f, 0.f, 0.f, 0.f};
#pragma unroll
  for (int i = 0; i < 8; ++i)
#pragma unroll
    for (int j = 0; j < 4; ++j) acc[i][j] = zero;

  bf16x8 af[4][2], bg0[2][2], bg1[2][2];

  // prologue: tile0 fully -> buf0; tile1.h0 -> buf1; wait tile0 (leave 2 in flight)
  G4_STG(0, 0, 0); G4_STG(0, 1, 0); G4_STG(0, 2, 0); G4_STG(0, 3, 0);
  G4_STG(1, 0, 1);
  G4_VM2(); G4_BAR();

  for (int it = 0; it < 3; ++it) {
    const int tO = 2 * it + 1, tE2 = 2 * it + 2, tO2 = 2 * it + 3;
    // ph1: E quad(0,0)
    G4_LDA(0, 0); G4_LDB(0, 0, bg0); G4_STG(1, 1, tO); G4_LGKM8(); G4_BAR(); G4_LGKM0();
    G4_PRIO1(); G4_QUAD(0, 0, bg0); G4_PRIO0(); G4_BAR();
    // ph2: E quad(0,1)
    G4_LDB(0, 1, bg1); G4_STG(1, 2, tO); G4_BAR(); G4_LGKM0();
    G4_PRIO1(); G4_QUAD(0, 1, bg1); G4_PRIO0(); G4_BAR();
    // ph3: E quad(1,1)
    G4_LDA(0, 1); G4_STG(1, 3, tO); G4_BAR(); G4_LGKM0();
    G4_PRIO1(); G4_QUAD(1, 1, bg1); G4_PRIO0(); G4_BAR();
    // ph4: E quad(1,0)  [regs only; buf0 free -> start tE2; wait O tile landed]
    G4_STG(0, 0, tE2); G4_VM2(); G4_BAR();
    G4_PRIO1(); G4_QUAD(1, 0, bg0); G4_PRIO0(); G4_BAR();
    // ph5: O quad(0,0)
    G4_LDA(1, 0); G4_LDB(1, 0, bg0); G4_STG(0, 1, tE2); G4_LGKM8(); G4_BAR(); G4_LGKM0();
    G4_PRIO1(); G4_QUAD(0, 0, bg0); G4_PRIO0(); G4_BAR();
    // ph6: O quad(0,1)
    G4_LDB(1, 1, bg1); G4_STG(0, 2, tE2); G4_BAR(); G4_LGKM0();
    G4_PRIO1(); G4_QUAD(0, 1, bg1); G4_PRIO0(); G4_BAR();
    // ph7: O quad(1,1)
    G4_LDA(1, 1); G4_STG(0, 3, tE2); G4_BAR(); G4_LGKM0();
    G4_PRIO1(); G4_QUAD(1, 1, bg1); G4_PRIO0(); G4_BAR();
    // ph8: O quad(1,0)  [buf1 free -> start tO2; wait tE2 landed]
    G4_STG(1, 0, tO2); G4_VM2(); G4_BAR();
    G4_PRIO1(); G4_QUAD(1, 0, bg0); G4_PRIO0(); G4_BAR();
  }

  // drain iteration: tiles 6 (buf0) and 7 (buf1)
  G4_LDA(0, 0); G4_LDB(0, 0, bg0); G4_STG(1, 1, 7); G4_LGKM8(); G4_BAR(); G4_LGKM0();
  G4_PRIO1(); G4_QUAD(0, 0, bg0); G4_PRIO0(); G4_BAR();
  G4_LDB(0, 1, bg1); G4_STG(1, 2, 7); G4_BAR(); G4_LGKM0();
  G4_PRIO1(); G4_QUAD(0, 1, bg1); G4_PRIO0(); G4_BAR();
  G4_LDA(0, 1); G4_STG(1, 3, 7); G4_BAR(); G4_LGKM0();
  G4_PRIO1(); G4_QUAD(1, 1, bg1); G4_PRIO0(); G4_BAR();
  G4_VM0(); G4_BAR();
  G4_PRIO1(); G4_QUAD(1, 0, bg0); G4_PRIO0(); G4_BAR();
  G4_LDA(1, 0); G4_LDB(1, 0, bg0); G4_BAR(); G4_LGKM0();
  G4_PRIO1(); G4_QUAD(0, 0, bg0); G4_PRIO0(); G4_BAR();
  G4_LDB(1, 1, bg1); G4_BAR(); G4_LGKM0();
  G4_PRIO1(); G4_QUAD(0, 1, bg1); G4_PRIO0(); G4_BAR();
  G4_LDA(1, 1); G4_BAR(); G4_LGKM0();
  G4_PRIO1(); G4_QUAD(1, 1, bg1); G4_PRIO0(); G4_BAR();
  G4_PRIO1(); G4_QUAD(1, 0, bg0); G4_PRIO0(); G4_BAR();

  // ---- colmax epilogue (reuse LDS as float scratch; all buffer reads done) ----
  float* smf = (float*)sm;
  float mv[4];
#pragma unroll
  for (int nj = 0; nj < 4; ++nj) {
    float m = -1e30f;
#pragma unroll
    for (int mi = 0; mi < 8; ++mi)
#pragma unroll
      for (int r = 0; r < 4; ++r) m = fmaxf(m, acc[mi][nj][r]);
    m = fmaxf(m, __shfl_xor(m, 16));
    m = fmaxf(m, __shfl_xor(m, 32));
    mv[nj] = m;
  }
  const float sel = (fq == 0) ? mv[0] : (fq == 1) ? mv[1] : (fq == 2) ? mv[2] : mv[3];
  smf[wm * 256 + wn * 64 + fq * 16 + fr] = sel;
  __syncthreads();
  if (tid < 256) {
    outp2[(size_t)rowTile * 1024 + colBase + tid] = fmaxf(smf[tid], smf[256 + tid]);
  }
}

// =====================================================================================
// Fused gmax reduce + cvec, COALESCED GEMV. 128 blocks (4/batch). Per block:
// gm[t] = max over only the ceil(cnt/128) real pg slots, with b2 baseline (invisible
// rows contribute exactly b2); then wave-per-row dot: lane holds w3[p][lane*4..+4]
// (float4, coalesced) x gm (from LDS), shuffle-reduce over 64.
// =====================================================================================
__global__ __launch_bounds__(256) void gmax_cvec_kernel(
    const float* __restrict__ pg, const float* __restrict__ w3,
    float* __restrict__ cvec, const int* __restrict__ cnt,
    const float* __restrict__ b2) {
  __shared__ float gm[256];
  const int b = blockIdx.x >> 2, quarter = blockIdx.x & 3;
  const int t = threadIdx.x;
  const int c = cnt[b];
  const int nt = (c + 127) >> 7;
  float m = (c < 4096) ? b2[t] : -1e30f;
  for (int s = 0; s < nt; ++s) m = fmaxf(m, pg[((size_t)b * 32 + s) * 256 + t]);
  gm[t] = m;
  __syncthreads();
  const int lane = t & 63, wv = t >> 6;
  const float g0 = gm[lane * 4 + 0];
  const float g1 = gm[lane * 4 + 1];
  const float g2v = gm[lane * 4 + 2];
  const float g3 = gm[lane * 4 + 3];
  for (int pp = 0; pp < 32; ++pp) {
    const int p = quarter * 128 + wv * 32 + pp;
    const float4 wr = *(const float4*)(w3 + (size_t)p * 512 + lane * 4);
    float s = wr.x * g0 + wr.y * g1 + wr.z * g2v + wr.w * g3;
    for (int o = 32; o; o >>= 1) s += __shfl_xor(s, o);
    if (lane == 0) cvec[b * 512 + p] = s;
  }
}

// =====================================================================================
// K_h: (+cvec) + LayerNorm(512) + relu in place on h46 (compacted).  R1-proven
// 32768-block version: rows < cnt: LN+relu; rows [cnt, ceil256): zero (gemm4 reads
// 256-row tiles); rows >= ceil256: untouched (no readers).
// =====================================================================================
__global__ __launch_bounds__(256) void ln2_kernel(
    unsigned short* __restrict__ h46, const int* __restrict__ cnt,
    const float* __restrict__ cvec,
    const float* __restrict__ g2, const float* __restrict__ be2) {
  const int lane = threadIdx.x & 63;
  const int wv = threadIdx.x >> 6;
  const size_t p = (size_t)blockIdx.x * 4 + wv;
  const int cb = cnt[p >> 12];
  const int pin = (int)(p & 4095);
  const int ceilv = (cb + 255) & ~255;
  if (pin >= ceilv) return;
  unsigned short* row = h46 + p * 512;
  const int c0 = lane * 8;
  if (pin >= cb) {                            // straddle zero-fill
    const uint4 z = {0, 0, 0, 0};
    *(uint4*)(row + c0) = z;
    return;
  }
  const int b = (int)(p >> 12);
  union { uint4 v; unsigned short s[8]; } in;
  in.v = *(const uint4*)(row + c0);
  float cv[8];
  *(float4*)(cv) = *(const float4*)(cvec + b * 512 + c0);
  *(float4*)(cv + 4) = *(const float4*)(cvec + b * 512 + c0 + 4);
  float f[8];
  float s = 0.f;
#pragma unroll
  for (int k = 0; k < 8; ++k) { f[k] = bf2f(in.s[k]) + cv[k]; s += f[k]; }
  for (int o = 32; o; o >>= 1) s += __shfl_xor(s, o);
  const float mu = s * (1.f / 512.f);
  float q = 0.f;
#pragma unroll
  for (int k = 0; k < 8; ++k) { const float d = f[k] - mu; q += d * d; }
  for (int o = 32; o; o >>= 1) q += __shfl_xor(q, o);
  const float rs = rsqrtf(q * (1.f / 512.f) + LN_EPS);
  union { uint4 v; unsigned short s[8]; } outv;
#pragma unroll
  for (int k = 0; k < 8; ++k) {
    const float y = fmaxf((f[k] - mu) * rs * g2[c0 + k] + be2[c0 + k], 0.f);
    outv.s[k] = f2bf_bits(y);
  }
  *(uint4*)(row + c0) = outv.v;
}

// =====================================================================================
// K_j: out[b][f] = max over the ceil(cnt/256) real pmax tiles, with 0 baseline when
// any row is invisible (h7 = 0 there), + b4[f].
// =====================================================================================
__global__ __launch_bounds__(256) void final_kernel(
    const float* __restrict__ pmax, const float* __restrict__ b4,
    float* __restrict__ out, const int* __restrict__ cnt) {
  const int idx = blockIdx.x * 256 + threadIdx.x;
  const int b = idx >> 10, f = idx & 1023;
  const int c = cnt[b];
  const int nt = (c + 255) >> 8;
  float m = (c < 4096) ? 0.f : -1e30f;
  for (int r = 0; r < nt; ++r) m = fmaxf(m, pmax[((size_t)(b * 16 + r)) * 1024 + f]);
  out[idx] = m + b4[f];
}

// =====================================================================================
extern "C" void kernel_launch(void* const* d_in, const int* in_sizes, int n_in,
                              void* d_out, int out_size, void* d_ws, size_t ws_size,
                              hipStream_t stream) {
  const float* points = (const float*)d_in[0];
  const int* mask = (const int*)d_in[1];
  const float* w1 = (const float*)d_in[2];
  const float* g1 = (const float*)d_in[3];
  const float* be1 = (const float*)d_in[4];
  const float* w2 = (const float*)d_in[5];
  const float* b2 = (const float*)d_in[6];
  const float* w3 = (const float*)d_in[7];
  const float* g2 = (const float*)d_in[8];
  const float* be2 = (const float*)d_in[9];
  const float* w4 = (const float*)d_in[10];
  const float* b4 = (const float*)d_in[11];
  float* out = (float*)d_out;
  char* ws = (char*)d_ws;

  const size_t OFF_H46 = 0;                          // 134217728 B (bf16 131072x512)
  const size_t OFF_H2 = 134217728;                   //  33554432 B (bf16 131072x128)
  const size_t OFF_W2B = OFF_H2 + 33554432;          //     65536 B
  const size_t OFF_W4B = OFF_W2B + 65536;            //   1048576 B
  const size_t OFF_W23B = OFF_W4B + 1048576;         //    131072 B (bf16 512x128)
  const size_t OFF_VECB = OFF_W23B + 131072;         //      2048 B (f32 512)
  const size_t OFF_PG = OFF_VECB + 2048;             //   1048576 B (f32 1024x256)
  const size_t OFF_CVEC = OFF_PG + 1048576;          //     65536 B
  const size_t OFF_PMAX = OFF_CVEC + 65536;          //   4194304 B (uses 2 MB)
  const size_t OFF_CNT = OFF_PMAX + 4194304;         //      4096 B
  const size_t OFF_NEWROW = OFF_CNT + 4096;          //    524288 B
  const size_t OFF_LNP = OFF_NEWROW + 524288;        //        64 B (f32 x 9, LN1 params)

  unsigned short* h2 = (unsigned short*)(ws + OFF_H2);
  unsigned short* h46 = (unsigned short*)(ws + OFF_H46);
  unsigned short* w2b = (unsigned short*)(ws + OFF_W2B);
  unsigned short* w4b = (unsigned short*)(ws + OFF_W4B);
  unsigned short* w23b = (unsigned short*)(ws + OFF_W23B);
  float* vecb = (float*)(ws + OFF_VECB);
  float* pg = (float*)(ws + OFF_PG);
  float* cvecp = (float*)(ws + OFF_CVEC);
  float* pmaxp = (float*)(ws + OFF_PMAX);
  int* cntp = (int*)(ws + OFF_CNT);
  int* newrow = (int*)(ws + OFF_NEWROW);
  float* lnp = (float*)(ws + OFF_LNP);

  // one-time: allow 128 KiB dynamic LDS for the 8-phase GEMM (host config, not a
  // stream op -- graph-capture safe)
  static bool s_attr_done = false;
  if (!s_attr_done) {
    hipFuncSetAttribute((const void*)gemm4_8ph,
                        hipFuncAttributeMaxDynamicSharedMemorySize, 131072);
    s_attr_done = true;
  }

  // 0. visible-first compaction map per batch (+ block 32: closed-form LN1 params)
  perm_kernel<<<33, 256, 0, stream>>>(mask, newrow, cntp, w1, lnp);
  // 1. conv1 + CLOSED-FORM LN1 + relu -> h2; tails: wconv + W23/vecb precompute
  conv1_ln_kernel<<<32768 + 2176 + 256, 256, 0, stream>>>(
      points, w1, g1, be1, h2, newrow, cntp, w2, b2, w3, w4, w2b, w4b, w23b, vecb,
      lnp);
  // 2. fused A-resident PAIRED: pg = colmax(h2@w2^T + b2) AND h46 = h2@W23^T + vecb
  gemm23_fused<<<3072, 256, 0, stream>>>(h2, w2b, w23b, h46, pg, b2, vecb, cntp);
  // 3. gmax + cvec (coalesced GEMV, 128 blocks, cnt-bounded with b2 baseline)
  gmax_cvec_kernel<<<128, 256, 0, stream>>>(pg, w3, cvecp, cntp, b2);
  // 4. (+cvec) + LN2 + relu in place; zero straddle rows [cnt, ceil256)
  ln2_kernel<<<32768, 256, 0, stream>>>(h46, cntp, cvecp, g2, be2);
  // 5. h7 colmax -> pmax, 256x256 8-phase (R1/R5 proven mapping)
  gemm4_8ph<<<2048, 512, 131072, stream>>>(h46, w4b, pmaxp, cntp);
  // 6. out = max over real row-blocks + b4 (0 baseline for invisible rows)
  final_kernel<<<128, 256, 0, stream>>>(pmaxp, b4, out, cntp);
}